// Round 2
// baseline (2325.168 us; speedup 1.0000x reference)
//
#include <hip/hip_runtime.h>
#include <math.h>

#define NP 4096

// ---------------- helpers ----------------
__device__ inline unsigned fenc(float f){
  unsigned b = __float_as_uint(f);
  return (b & 0x80000000u) ? ~b : (b | 0x80000000u);
}
__device__ inline float fdec(unsigned u){
  return (u & 0x80000000u) ? __uint_as_float(u ^ 0x80000000u) : __uint_as_float(~u);
}

// ---------------- T-net ----------------
__global__ __launch_bounds__(256) void t1_kernel(const float* __restrict__ pc,
    const float* __restrict__ w1, const float* __restrict__ b1, float* __restrict__ t1){
  int i = blockIdx.x*4 + (threadIdx.x>>6);
  int o = threadIdx.x & 63;
  float p0 = pc[i*3+0], p1 = pc[i*3+1], p2 = pc[i*3+2];
  float v = p0*w1[o] + p1*w1[64+o] + p2*w1[128+o] + b1[o];
  t1[i*64+o] = fmaxf(v, 0.f);
}

__global__ __launch_bounds__(256) void tnet_tail_kernel(const unsigned* __restrict__ tpool,
    const float* __restrict__ w3, const float* __restrict__ b3,
    const float* __restrict__ w4, const float* __restrict__ b4,
    float* __restrict__ qmat, float* __restrict__ rout){
  __shared__ float tp[1024];
  __shared__ float t3[256];
  __shared__ float t4[9];
  int tid = threadIdx.x;
  for (int j = tid; j < 1024; j += 256) tp[j] = fdec(tpool[j]);
  __syncthreads();
  float acc = b3[tid];
  for (int d = 0; d < 1024; ++d) acc += tp[d]*w3[d*256+tid];
  t3[tid] = fmaxf(acc, 0.f);
  __syncthreads();
  if (tid < 9){
    float a = b4[tid];
    for (int d = 0; d < 256; ++d) a += t3[d]*w4[d*9+tid];
    t4[tid] = a;
  }
  __syncthreads();
  if (tid == 0){
    float a00=t4[0], a01=t4[1], a02=t4[2];
    float a10=t4[3], a11=t4[4], a12=t4[5];
    float a20=t4[6], a21=t4[7], a22=t4[8];
    // Householder QR, LAPACK sign convention (beta = -sign(alpha)*norm)
    float tau0 = 0.f, v1 = 0.f, v2 = 0.f;
    float xn2 = a10*a10 + a20*a20;
    if (xn2 > 0.f){
      float alpha = a00;
      float nrm = sqrtf(alpha*alpha + xn2);
      float beta = (alpha >= 0.f) ? -nrm : nrm;
      tau0 = (beta - alpha)/beta;
      float inv = 1.f/(alpha - beta);
      v1 = a10*inv; v2 = a20*inv;
      float s1 = a01 + v1*a11 + v2*a21; s1 *= tau0;
      a01 -= s1; a11 -= v1*s1; a21 -= v2*s1;
      float s2 = a02 + v1*a12 + v2*a22; s2 *= tau0;
      a02 -= s2; a12 -= v1*s2; a22 -= v2*s2;
      a00 = beta;
    }
    float tau1 = 0.f, wv = 0.f;
    float xn1 = a21*a21;
    if (xn1 > 0.f){
      float alpha = a11;
      float nrm = sqrtf(alpha*alpha + xn1);
      float beta = (alpha >= 0.f) ? -nrm : nrm;
      tau1 = (beta - alpha)/beta;
      wv = a21/(alpha - beta);
      float s = a12 + wv*a22; s *= tau1;
      a12 -= s; a22 -= wv*s;
      a11 = beta;
    }
    rout[0]=a00; rout[1]=a01; rout[2]=a02;
    rout[3]=0.f; rout[4]=a11; rout[5]=a12;
    rout[6]=0.f; rout[7]=0.f; rout[8]=a22;
    // Q = H0 * H1
    float M[3][3] = {{1,0,0},{0,1,0},{0,0,1}};
    M[1][1] -= tau1;     M[1][2] -= tau1*wv;
    M[2][1] -= tau1*wv;  M[2][2] -= tau1*wv*wv;
    #pragma unroll
    for (int c = 0; c < 3; ++c){
      float p = M[0][c] + v1*M[1][c] + v2*M[2][c];
      qmat[0*3+c] = M[0][c] - tau0*p;
      qmat[1*3+c] = M[1][c] - tau0*v1*p;
      qmat[2*3+c] = M[2][c] - tau0*v2*p;
    }
  }
}

__global__ __launch_bounds__(256) void xform_kernel(const float* __restrict__ pc,
    const float* __restrict__ q, float* __restrict__ x){
  int i = blockIdx.x*256 + threadIdx.x;
  if (i >= NP) return;
  float p0 = pc[i*3+0], p1 = pc[i*3+1], p2 = pc[i*3+2];
  x[i*3+0] = p0*q[0] + p1*q[3] + p2*q[6];
  x[i*3+1] = p0*q[1] + p1*q[4] + p2*q[7];
  x[i*3+2] = p0*q[2] + p1*q[5] + p2*q[8];
}

// ---------------- generic f32 GEMM (M x K @ K x ncols), 64x64 tiles ----------------
// STORE: write C; COLMAX: atomic col-max (encoded); BT: B is [ncols, K] row-major (B^T);
// D2EPI: out = bias[col] - 2*acc (distance-matrix epilogue, bias = col squared-norms)
template<int STORE, int COLMAX, int BT, int D2EPI>
__global__ __launch_bounds__(256) void gemm_kernel(
    const float* __restrict__ A, int lda,
    const float* __restrict__ B, int ldb,
    const float* __restrict__ bias,
    float* __restrict__ C, unsigned* __restrict__ cmax,
    int kloop, int kreal, int ncols, int remap_thresh, int remap_shift){
  __shared__ float As[32][68];
  __shared__ float Bs[32][68];
  int tid = threadIdx.x;
  int nbx = ncols >> 6;
  int bx = blockIdx.x % nbx, by = blockIdx.x / nbx;
  int tx = tid & 15, ty = tid >> 4;
  int row0 = by*64, col0 = bx*64;
  float acc[4][4];
  #pragma unroll
  for (int r = 0; r < 4; ++r)
    #pragma unroll
    for (int c = 0; c < 4; ++c) acc[r][c] = 0.f;

  for (int kt = 0; kt < kloop; kt += 32){
    // stage A (64 rows x 32 k), transposed into As[k][m]
    {
      int m = tid & 63, kq = tid >> 6;
      #pragma unroll
      for (int h = 0; h < 2; ++h){
        int k4 = kq + h*4;
        float4 av = make_float4(0.f,0.f,0.f,0.f);
        if (kt + k4*4 < kreal)
          av = *(const float4*)&A[(size_t)(row0+m)*lda + kt + k4*4];
        As[k4*4+0][m] = av.x; As[k4*4+1][m] = av.y;
        As[k4*4+2][m] = av.z; As[k4*4+3][m] = av.w;
      }
    }
    // stage B (32 k x 64 cols)
    if (BT){
      int c = tid & 63, kq = tid >> 6;
      #pragma unroll
      for (int h = 0; h < 2; ++h){
        int k4 = kq + h*4;
        float4 bv = make_float4(0.f,0.f,0.f,0.f);
        if (kt + k4*4 < kreal)
          bv = *(const float4*)&B[(size_t)(col0+c)*ldb + kt + k4*4];
        Bs[k4*4+0][c] = bv.x; Bs[k4*4+1][c] = bv.y;
        Bs[k4*4+2][c] = bv.z; Bs[k4*4+3][c] = bv.w;
      }
    } else {
      int k = tid & 31, cq = tid >> 5;
      #pragma unroll
      for (int h = 0; h < 2; ++h){
        int c4 = cq + h*8;
        int krow = kt + k;
        int brow = (krow >= remap_thresh) ? krow + remap_shift : krow;
        float4 bv = *(const float4*)&B[(size_t)brow*ldb + col0 + c4*4];
        *(float4*)&Bs[k][c4*4] = bv;
      }
    }
    __syncthreads();
    #pragma unroll
    for (int k = 0; k < 32; ++k){
      float4 a4 = *(const float4*)&As[k][ty*4];
      float4 b4 = *(const float4*)&Bs[k][tx*4];
      float av[4] = {a4.x, a4.y, a4.z, a4.w};
      float bv[4] = {b4.x, b4.y, b4.z, b4.w};
      #pragma unroll
      for (int r = 0; r < 4; ++r)
        #pragma unroll
        for (int c = 0; c < 4; ++c) acc[r][c] += av[r]*bv[c];
    }
    __syncthreads();
  }
  // epilogue
  float bvv[4];
  #pragma unroll
  for (int c = 0; c < 4; ++c) bvv[c] = bias[col0 + tx*4 + c];
  float val[4][4];
  #pragma unroll
  for (int r = 0; r < 4; ++r)
    #pragma unroll
    for (int c = 0; c < 4; ++c)
      val[r][c] = D2EPI ? (bvv[c] - 2.f*acc[r][c]) : (acc[r][c] + bvv[c]);
  if (STORE){
    #pragma unroll
    for (int r = 0; r < 4; ++r){
      float4 v = make_float4(val[r][0], val[r][1], val[r][2], val[r][3]);
      *(float4*)&C[(size_t)(row0 + ty*4 + r)*ncols + col0 + tx*4] = v;
    }
  }
  if (COLMAX){
    float cm[4];
    #pragma unroll
    for (int c = 0; c < 4; ++c)
      cm[c] = fmaxf(fmaxf(val[0][c], val[1][c]), fmaxf(val[2][c], val[3][c]));
    float* red = (float*)As;
    #pragma unroll
    for (int c = 0; c < 4; ++c) red[ty*64 + tx*4 + c] = cm[c];
    __syncthreads();
    if (tid < 64){
      float m = red[tid];
      #pragma unroll
      for (int t = 1; t < 16; ++t) m = fmaxf(m, red[t*64 + tid]);
      atomicMax(&cmax[col0 + tid], fenc(m));
    }
  }
}

// ---------------- top-k extraction (per-wave, row in LDS) ----------------
template<int K>
__device__ inline void extract_topk(float* d2row, int lane, int* __restrict__ nbr_row){
  float gmin[8]; int gidx[8];
  const int basej = lane*64;
  #pragma unroll
  for (int g = 0; g < 8; ++g){
    float mv = 3e38f; int mi = basej + g*8;
    #pragma unroll
    for (int e = 0; e < 8; ++e){
      int j = basej + g*8 + e;
      float v = d2row[j];
      bool c = v < mv; mv = c ? v : mv; mi = c ? j : mi;
    }
    gmin[g] = mv; gidx[g] = mi;
  }
  float lv; int li;
  {
    lv = gmin[0]; li = gidx[0];
    #pragma unroll
    for (int g = 1; g < 8; ++g){
      bool c = (gmin[g] < lv) || (gmin[g] == lv && gidx[g] < li);
      lv = c ? gmin[g] : lv; li = c ? gidx[g] : li;
    }
  }
  int keep = 0;
  for (int r = 0; r < K; ++r){
    float v = lv; int ix = li;
    #pragma unroll
    for (int off = 32; off; off >>= 1){
      float ov = __shfl_xor(v, off);
      int oi = __shfl_xor(ix, off);
      bool c = (ov < v) || (ov == v && oi < ix);
      v = c ? ov : v; ix = c ? oi : ix;
    }
    if (lane == r) keep = ix;
    if ((ix >> 6) == lane){
      d2row[ix] = 3e38f;
      int g = (ix >> 3) & 7;
      float mv = 3e38f; int mi = basej + g*8;
      #pragma unroll
      for (int e = 0; e < 8; ++e){
        int j = basej + g*8 + e;
        float vv = d2row[j];
        bool cc = vv < mv; mv = cc ? vv : mv; mi = cc ? j : mi;
      }
      #pragma unroll
      for (int g2 = 0; g2 < 8; ++g2){ if (g2 == g){ gmin[g2] = mv; gidx[g2] = mi; } }
      lv = gmin[0]; li = gidx[0];
      #pragma unroll
      for (int g = 1; g < 8; ++g){
        bool c = (gmin[g] < lv) || (gmin[g] == lv && gidx[g] < li);
        lv = c ? gmin[g] : lv; li = c ? gidx[g] : li;
      }
    }
  }
  if (lane < K) nbr_row[lane] = keep;
}

// kNN over 2-3 coordinate dims, fully fused (coords cached in LDS)
template<int D>
__global__ __launch_bounds__(256) void knn_small_kernel(const float* __restrict__ x,
    int dA, int dB, int dC, int* __restrict__ nbr){
  __shared__ float cs[D][NP];
  __shared__ float d2row[4][NP];
  int tid = threadIdx.x, lane = tid & 63, w = tid >> 6;
  for (int j = tid; j < NP; j += 256){
    cs[0][j] = x[j*3 + dA];
    cs[1][j] = x[j*3 + dB];
    if (D == 3) cs[2][j] = x[j*3 + dC];
  }
  __syncthreads();
  int i = blockIdx.x*4 + w;
  float xi[D];
  xi[0] = x[i*3 + dA]; xi[1] = x[i*3 + dB];
  if (D == 3) xi[2] = x[i*3 + dC];
  for (int jc = 0; jc < 64; ++jc){
    int j = jc*64 + lane;
    float sq = 0.f, dot = 0.f;
    #pragma unroll
    for (int c = 0; c < D; ++c){ float v = cs[c][j]; sq += v*v; dot += v*xi[c]; }
    d2row[w][j] = sq - 2.f*dot;   // sq_i dropped: rank-invariant shift
  }
  extract_topk<20>(&d2row[w][0], lane, &nbr[i*20]);
}

// top-k from a precomputed (chunked) d2 matrix
template<int K>
__global__ __launch_bounds__(256) void topk_kernel(const float* __restrict__ d2m,
    int* __restrict__ nbr_chunk){
  __shared__ float d2row[4][NP];
  int tid = threadIdx.x, lane = tid & 63, w = tid >> 6;
  int il = blockIdx.x*4 + w;
  #pragma unroll
  for (int h = 0; h < 16; ++h){
    int j4 = lane + h*64;
    float4 v = *(const float4*)&d2m[(size_t)il*NP + j4*4];
    *(float4*)&d2row[w][j4*4] = v;
  }
  extract_topk<K>(&d2row[w][0], lane, &nbr_chunk[il*K]);
}

// ---------------- graph utilities ----------------
__global__ __launch_bounds__(256) void sq_kernel(const float* __restrict__ f, int ld, int D,
    float* __restrict__ sq){
  int i = blockIdx.x*256 + threadIdx.x;
  if (i >= NP) return;
  float s = 0.f;
  for (int c = 0; c < D; ++c){ float v = f[(size_t)i*ld + c]; s += v*v; }
  sq[i] = s;
}

__global__ __launch_bounds__(256) void deg_kernel(const int* __restrict__ nbr, int total,
    int* __restrict__ deg){
  int e = blockIdx.x*256 + threadIdx.x;
  if (e < total) atomicAdd(&deg[nbr[e]], 1);
}

// DGL GraphConv norm='both': out[i] = ((1/sqrt(k)) * sum_j x[j]/sqrt(deg_j)) @ W + b
template<int DIN, int DOUT>
__global__ __launch_bounds__(256) void gc_kernel(const int* __restrict__ nbr, int k, float kscale,
    const int* __restrict__ deg, const float* __restrict__ x, int ldx,
    const float* __restrict__ w, const float* __restrict__ b,
    float* __restrict__ out, int ldo){
  __shared__ float aggs[4][DIN];
  int tid = threadIdx.x, lane = tid & 63, wv = tid >> 6;
  int i = blockIdx.x*4 + wv;
  if (lane < DIN){
    float agg = 0.f;
    for (int j = 0; j < k; ++j){
      int idx = nbr[i*k + j];
      float rs = rsqrtf(fmaxf((float)deg[idx], 1.0f));
      agg += x[(size_t)idx*ldx + lane] * rs;
    }
    aggs[wv][lane] = agg * kscale;
  }
  __syncthreads();
  if (lane < DOUT){
    float o = b[lane];
    #pragma unroll 8
    for (int d = 0; d < DIN; ++d) o += aggs[wv][d] * w[d*DOUT + lane];
    out[(size_t)i*ldo + lane] = o;
  }
}

// ---------------- GAT pieces ----------------
__global__ __launch_bounds__(256) void crow_kernel(const unsigned* __restrict__ fc0max,
    const float* __restrict__ ws_, const float* __restrict__ wd_,
    float* __restrict__ c_s, float* __restrict__ c_d){
  __shared__ float hr[1024];
  int col = (blockIdx.x >> 1)*256 + threadIdx.x;
  const float* W = (blockIdx.x & 1) ? wd_ : ws_;
  float* outp = (blockIdx.x & 1) ? c_d : c_s;
  for (int j = threadIdx.x; j < 1024; j += 256) hr[j] = fdec(fc0max[j]);
  __syncthreads();
  float acc = 0.f;
  for (int d = 0; d < 1024; ++d) acc += hr[d]*W[(size_t)(192+d)*1024 + col];
  outp[col] = acc;
}

// GATv2 with online softmax; 4 heads = 4 waves; 16 nodes/block; col-max accumulated in regs
__global__ __launch_bounds__(256) void gat_kernel(const int* __restrict__ nbr,
    const float* __restrict__ fs, const float* __restrict__ fd,
    const float* __restrict__ a, unsigned* __restrict__ gmax){
  int tid = threadIdx.x, lane = tid & 63, h = tid >> 6;
  float4 at = *(const float4*)&a[h*256 + lane*4];
  float av[4] = {at.x, at.y, at.z, at.w};
  float runmax[4] = {-3e38f, -3e38f, -3e38f, -3e38f};
  for (int it = 0; it < 16; ++it){
    int i = blockIdx.x*16 + it;
    float4 fdv4 = *(const float4*)&fd[(size_t)i*1024 + h*256 + lane*4];
    float fdv[4] = {fdv4.x, fdv4.y, fdv4.z, fdv4.w};
    float m = -3e38f, l = 0.f;
    float o[4] = {0.f, 0.f, 0.f, 0.f};
    for (int j = 0; j < 20; ++j){
      int nb = nbr[i*20 + j];
      float4 fv4 = *(const float4*)&fs[(size_t)nb*1024 + h*256 + lane*4];
      float fv[4] = {fv4.x, fv4.y, fv4.z, fv4.w};
      float p = 0.f;
      #pragma unroll
      for (int c = 0; c < 4; ++c){
        float e = fv[c] + fdv[c];
        e = (e > 0.f) ? e : 0.2f*e;
        p += e*av[c];
      }
      #pragma unroll
      for (int off = 32; off; off >>= 1) p += __shfl_xor(p, off);
      float mn = fmaxf(m, p);
      float scale = __expf(m - mn);
      float wexp = __expf(p - mn);
      l = l*scale + wexp;
      #pragma unroll
      for (int c = 0; c < 4; ++c) o[c] = o[c]*scale + wexp*fv[c];
      m = mn;
    }
    float inv = 1.f/l;
    #pragma unroll
    for (int c = 0; c < 4; ++c) runmax[c] = fmaxf(runmax[c], o[c]*inv);
  }
  #pragma unroll
  for (int c = 0; c < 4; ++c) atomicMax(&gmax[h*256 + lane*4 + c], fenc(runmax[c]));
}

__global__ __launch_bounds__(256) void head_kernel(const unsigned* __restrict__ gmax,
    const float* __restrict__ gb, const float* __restrict__ w1, const float* __restrict__ b1,
    const float* __restrict__ w2, const float* __restrict__ b2,
    const float* __restrict__ w3, const float* __restrict__ b3, float* __restrict__ out){
  __shared__ float hm[1024];
  __shared__ float s1[256];
  __shared__ float s2[64];
  int tid = threadIdx.x;
  for (int j = tid; j < 1024; j += 256) hm[j] = fdec(gmax[j]) + gb[j];
  __syncthreads();
  float acc = b1[tid];
  for (int d = 0; d < 1024; ++d) acc += hm[d]*w1[d*256+tid];
  s1[tid] = fmaxf(acc, 0.f);
  __syncthreads();
  if (tid < 64){
    float a2 = b2[tid];
    for (int d = 0; d < 256; ++d) a2 += s1[d]*w2[d*64+tid];
    s2[tid] = fmaxf(a2, 0.f);
  }
  __syncthreads();
  if (tid < 40){
    float a3 = b3[tid];
    for (int d = 0; d < 64; ++d) a3 += s2[d]*w3[d*40+tid];
    out[tid] = a3;
  }
}

// ---------------- launch ----------------
extern "C" void kernel_launch(void* const* d_in, const int* in_sizes, int n_in,
                              void* d_out, int out_size, void* d_ws, size_t ws_size,
                              hipStream_t stream){
  (void)in_sizes; (void)n_in; (void)out_size; (void)ws_size;
  const float* pc    = (const float*)d_in[0];
  const float* t_w1  = (const float*)d_in[1];
  const float* t_b1  = (const float*)d_in[2];
  const float* t_w2  = (const float*)d_in[3];
  const float* t_b2  = (const float*)d_in[4];
  const float* t_w3  = (const float*)d_in[5];
  const float* t_b3  = (const float*)d_in[6];
  const float* t_w4  = (const float*)d_in[7];
  const float* t_b4  = (const float*)d_in[8];
  const float* gc1_w = (const float*)d_in[9];
  const float* gc1_b = (const float*)d_in[10];
  const float* gc_w  = (const float*)d_in[11];
  const float* gc_b  = (const float*)d_in[12];
  const float* gp1_w = (const float*)d_in[13];
  const float* gp1_b = (const float*)d_in[14];
  const float* gp2_w = (const float*)d_in[15];
  const float* gp2_b = (const float*)d_in[16];
  const float* fc0_w = (const float*)d_in[17];
  const float* fc0_b = (const float*)d_in[18];
  const float* gat_ws= (const float*)d_in[19];
  const float* gat_wd= (const float*)d_in[20];
  const float* gat_a = (const float*)d_in[21];
  const float* gat_b = (const float*)d_in[22];
  const float* fc1_w = (const float*)d_in[23];
  const float* fc1_b = (const float*)d_in[24];
  const float* fc2_w = (const float*)d_in[25];
  const float* fc2_b = (const float*)d_in[26];
  const float* fc3_w = (const float*)d_in[27];
  const float* fc3_b = (const float*)d_in[28];
  float* out = (float*)d_out;

  char* basep = (char*)d_ws; size_t off = 0;
  auto alloc = [&](size_t bytes)->void*{
    void* p = basep + off; off += (bytes + 255) & ~(size_t)255; return p;
  };
  float* t1      = (float*)alloc((size_t)NP*64*4);
  float* x       = (float*)alloc((size_t)NP*3*4);
  float* qmat    = (float*)alloc(64);
  unsigned* tpool  = (unsigned*)alloc(1024*4);
  unsigned* fc0max = (unsigned*)alloc(1024*4);
  unsigned* gatmax = (unsigned*)alloc(1024*4);
  float* c_s     = (float*)alloc(1024*4);
  float* c_d     = (float*)alloc(1024*4);
  float* tmp64   = (float*)alloc((size_t)NP*64*4);
  float* hfull   = (float*)alloc((size_t)NP*384*4);
  float* hp0     = (float*)alloc((size_t)NP*16*4);
  float* hp1     = (float*)alloc((size_t)NP*16*4);
  float* hp2     = (float*)alloc((size_t)NP*16*4);
  float* sqbuf   = (float*)alloc((size_t)NP*4);
  float* d2c     = (float*)alloc((size_t)1024*NP*4);
  int* nbr_g0    = (int*)alloc((size_t)NP*20*4);
  int* nbr_gxy   = (int*)alloc((size_t)NP*20*4);
  int* nbr_gyz   = (int*)alloc((size_t)NP*20*4);
  int* nbr_gxz   = (int*)alloc((size_t)NP*20*4);
  int* nbr_gf0   = (int*)alloc((size_t)NP*20*4);
  int* nbr_gf1   = (int*)alloc((size_t)NP*20*4);
  int* nbr_gp0   = (int*)alloc((size_t)NP*50*4);
  int* nbr_gp1   = (int*)alloc((size_t)NP*50*4);
  int* nbr_gp2   = (int*)alloc((size_t)NP*50*4);
  int* degs      = (int*)alloc((size_t)9*NP*4);
  float* fsb     = (float*)alloc((size_t)NP*1024*4);
  float* fdb     = (float*)alloc((size_t)NP*1024*4);

  const float KS20 = 0.22360679774997896f;   // 1/sqrt(20)
  const float KS50 = 0.14142135623730950f;   // 1/sqrt(50)
  const int NOMAP = 1 << 30;

  hipMemsetAsync(tpool,  0, 1024*4, stream);
  hipMemsetAsync(fc0max, 0, 1024*4, stream);
  hipMemsetAsync(gatmax, 0, 1024*4, stream);
  hipMemsetAsync(degs,   0, (size_t)9*NP*4, stream);

  // ---- T-net ----
  t1_kernel<<<NP/4, 256, 0, stream>>>(pc, t_w1, t_b1, t1);
  gemm_kernel<0,1,0,0><<<16*64, 256, 0, stream>>>(t1, 64, t_w2, 1024, t_b2,
      nullptr, tpool, 64, 64, 1024, NOMAP, 0);
  tnet_tail_kernel<<<1, 256, 0, stream>>>(tpool, t_w3, t_b3, t_w4, t_b4, qmat, out + 40);
  xform_kernel<<<16, 256, 0, stream>>>(pc, qmat, x);

  // ---- coordinate kNN graphs ----
  knn_small_kernel<3><<<NP/4, 256, 0, stream>>>(x, 0, 1, 2, nbr_g0);
  knn_small_kernel<2><<<NP/4, 256, 0, stream>>>(x, 0, 1, 0, nbr_gxy);
  knn_small_kernel<2><<<NP/4, 256, 0, stream>>>(x, 1, 2, 0, nbr_gyz);
  knn_small_kernel<2><<<NP/4, 256, 0, stream>>>(x, 0, 2, 0, nbr_gxz);
  deg_kernel<<<(NP*20+255)/256, 256, 0, stream>>>(nbr_g0,  NP*20, degs + 0*NP);
  deg_kernel<<<(NP*20+255)/256, 256, 0, stream>>>(nbr_gxy, NP*20, degs + 1*NP);
  deg_kernel<<<(NP*20+255)/256, 256, 0, stream>>>(nbr_gyz, NP*20, degs + 2*NP);
  deg_kernel<<<(NP*20+255)/256, 256, 0, stream>>>(nbr_gxz, NP*20, degs + 3*NP);

  // ---- main branch ----
  gc_kernel<3,64><<<NP/4, 256, 0, stream>>>(nbr_g0, 20, KS20, degs + 0*NP, x, 3,
      gc1_w, gc1_b, tmp64, 64);
  gc_kernel<64,64><<<NP/4, 256, 0, stream>>>(nbr_g0, 20, KS20, degs + 0*NP, tmp64, 64,
      gc_w + 0*4096, gc_b + 0*64, hfull + 0, 384);
  // gf0 = knn(h0, 20)
  sq_kernel<<<16, 256, 0, stream>>>(hfull + 0, 384, 64, sqbuf);
  for (int ch = 0; ch < 4; ++ch){
    gemm_kernel<1,0,1,1><<<64*16, 256, 0, stream>>>(hfull + (size_t)ch*1024*384, 384,
        hfull + 0, 384, sqbuf, d2c, nullptr, 64, 64, NP, NOMAP, 0);
    topk_kernel<20><<<256, 256, 0, stream>>>(d2c, nbr_gf0 + ch*1024*20);
  }
  deg_kernel<<<(NP*20+255)/256, 256, 0, stream>>>(nbr_gf0, NP*20, degs + 4*NP);
  gc_kernel<64,64><<<NP/4, 256, 0, stream>>>(nbr_gf0, 20, KS20, degs + 4*NP, hfull + 0, 384,
      gc_w + 1*4096, gc_b + 1*64, tmp64, 64);
  gc_kernel<64,64><<<NP/4, 256, 0, stream>>>(nbr_gf0, 20, KS20, degs + 4*NP, tmp64, 64,
      gc_w + 2*4096, gc_b + 2*64, hfull + 64, 384);
  // gf1 = knn(h1, 20)
  sq_kernel<<<16, 256, 0, stream>>>(hfull + 64, 384, 64, sqbuf);
  for (int ch = 0; ch < 4; ++ch){
    gemm_kernel<1,0,1,1><<<64*16, 256, 0, stream>>>(hfull + 64 + (size_t)ch*1024*384, 384,
        hfull + 64, 384, sqbuf, d2c, nullptr, 64, 64, NP, NOMAP, 0);
    topk_kernel<20><<<256, 256, 0, stream>>>(d2c, nbr_gf1 + ch*1024*20);
  }
  deg_kernel<<<(NP*20+255)/256, 256, 0, stream>>>(nbr_gf1, NP*20, degs + 5*NP);
  gc_kernel<64,64><<<NP/4, 256, 0, stream>>>(nbr_gf1, 20, KS20, degs + 5*NP, hfull + 64, 384,
      gc_w + 3*4096, gc_b + 3*64, hfull + 128, 384);

  // ---- plane branches ----
  int* nbr_pl[3] = {nbr_gxy, nbr_gyz, nbr_gxz};
  int* nbr_gp[3] = {nbr_gp0, nbr_gp1, nbr_gp2};
  float* hps[3]  = {hp0, hp1, hp2};
  for (int i = 0; i < 3; ++i){
    gc_kernel<3,16><<<NP/4, 256, 0, stream>>>(nbr_pl[i], 20, KS20, degs + (1+i)*NP, x, 3,
        gp1_w + i*48, gp1_b + i*16, hps[i], 16);
    sq_kernel<<<16, 256, 0, stream>>>(hps[i], 16, 16, sqbuf);
    for (int ch = 0; ch < 4; ++ch){
      gemm_kernel<1,0,1,1><<<64*16, 256, 0, stream>>>(hps[i] + (size_t)ch*1024*16, 16,
          hps[i], 16, sqbuf, d2c, nullptr, 32, 16, NP, NOMAP, 0);
      topk_kernel<50><<<256, 256, 0, stream>>>(d2c, nbr_gp[i] + ch*1024*50);
    }
    deg_kernel<<<(NP*50+255)/256, 256, 0, stream>>>(nbr_gp[i], NP*50, degs + (6+i)*NP);
    gc_kernel<16,64><<<NP/4, 256, 0, stream>>>(nbr_gp[i], 50, KS50, degs + (6+i)*NP,
        hps[i], 16, gp2_w + i*1024, gp2_b + i*64, hfull + 192 + 64*i, 384);
  }

  // ---- fc0 + max, then fs/fd GEMMs with h_ folded in as a per-column constant ----
  gemm_kernel<0,1,0,0><<<16*64, 256, 0, stream>>>(hfull, 384, fc0_w, 1024, fc0_b,
      nullptr, fc0max, 192, 192, 1024, NOMAP, 0);
  crow_kernel<<<8, 256, 0, stream>>>(fc0max, gat_ws, gat_wd, c_s, c_d);
  gemm_kernel<1,0,0,0><<<16*64, 256, 0, stream>>>(hfull, 384, gat_ws, 1024, c_s,
      fsb, nullptr, 384, 384, 1024, 192, 1024);
  gemm_kernel<1,0,0,0><<<16*64, 256, 0, stream>>>(hfull, 384, gat_wd, 1024, c_d,
      fdb, nullptr, 384, 384, 1024, 192, 1024);

  // ---- GATv2 + head ----
  gat_kernel<<<NP/16, 256, 0, stream>>>(nbr_g0, fsb, fdb, gat_a, gatmax);
  head_kernel<<<1, 256, 0, stream>>>(gatmax, gat_b, fc1_w, fc1_b, fc2_w, fc2_b,
      fc3_w, fc3_b, out);
}

// Round 3
// 1853.415 us; speedup vs baseline: 1.2545x; 1.2545x over previous
//
#include <hip/hip_runtime.h>
#include <math.h>

#define NP 4096

// ---------------- helpers ----------------
__device__ inline unsigned fenc(float f){
  unsigned b = __float_as_uint(f);
  return (b & 0x80000000u) ? ~b : (b | 0x80000000u);
}
__device__ inline float fdec(unsigned u){
  return (u & 0x80000000u) ? __uint_as_float(u ^ 0x80000000u) : __uint_as_float(~u);
}

// ---------------- T-net ----------------
__global__ __launch_bounds__(256) void t1_kernel(const float* __restrict__ pc,
    const float* __restrict__ w1, const float* __restrict__ b1, float* __restrict__ t1){
  int i = blockIdx.x*4 + (threadIdx.x>>6);
  int o = threadIdx.x & 63;
  float p0 = pc[i*3+0], p1 = pc[i*3+1], p2 = pc[i*3+2];
  float v = p0*w1[o] + p1*w1[64+o] + p2*w1[128+o] + b1[o];
  t1[i*64+o] = fmaxf(v, 0.f);
}

__global__ __launch_bounds__(256) void tnet_tail_kernel(const unsigned* __restrict__ tpool,
    const float* __restrict__ w3, const float* __restrict__ b3,
    const float* __restrict__ w4, const float* __restrict__ b4,
    float* __restrict__ qmat, float* __restrict__ rout){
  __shared__ float tp[1024];
  __shared__ float t3[256];
  __shared__ float t4[9];
  int tid = threadIdx.x;
  for (int j = tid; j < 1024; j += 256) tp[j] = fdec(tpool[j]);
  __syncthreads();
  float acc = b3[tid];
  for (int d = 0; d < 1024; ++d) acc += tp[d]*w3[d*256+tid];
  t3[tid] = fmaxf(acc, 0.f);
  __syncthreads();
  if (tid < 9){
    float a = b4[tid];
    for (int d = 0; d < 256; ++d) a += t3[d]*w4[d*9+tid];
    t4[tid] = a;
  }
  __syncthreads();
  if (tid == 0){
    float a00=t4[0], a01=t4[1], a02=t4[2];
    float a10=t4[3], a11=t4[4], a12=t4[5];
    float a20=t4[6], a21=t4[7], a22=t4[8];
    // Householder QR, LAPACK sign convention (beta = -sign(alpha)*norm)
    float tau0 = 0.f, v1 = 0.f, v2 = 0.f;
    float xn2 = a10*a10 + a20*a20;
    if (xn2 > 0.f){
      float alpha = a00;
      float nrm = sqrtf(alpha*alpha + xn2);
      float beta = (alpha >= 0.f) ? -nrm : nrm;
      tau0 = (beta - alpha)/beta;
      float inv = 1.f/(alpha - beta);
      v1 = a10*inv; v2 = a20*inv;
      float s1 = a01 + v1*a11 + v2*a21; s1 *= tau0;
      a01 -= s1; a11 -= v1*s1; a21 -= v2*s1;
      float s2 = a02 + v1*a12 + v2*a22; s2 *= tau0;
      a02 -= s2; a12 -= v1*s2; a22 -= v2*s2;
      a00 = beta;
    }
    float tau1 = 0.f, wv = 0.f;
    float xn1 = a21*a21;
    if (xn1 > 0.f){
      float alpha = a11;
      float nrm = sqrtf(alpha*alpha + xn1);
      float beta = (alpha >= 0.f) ? -nrm : nrm;
      tau1 = (beta - alpha)/beta;
      wv = a21/(alpha - beta);
      float s = a12 + wv*a22; s *= tau1;
      a12 -= s; a22 -= wv*s;
      a11 = beta;
    }
    rout[0]=a00; rout[1]=a01; rout[2]=a02;
    rout[3]=0.f; rout[4]=a11; rout[5]=a12;
    rout[6]=0.f; rout[7]=0.f; rout[8]=a22;
    // Q = H0 * H1
    float M[3][3] = {{1,0,0},{0,1,0},{0,0,1}};
    M[1][1] -= tau1;     M[1][2] -= tau1*wv;
    M[2][1] -= tau1*wv;  M[2][2] -= tau1*wv*wv;
    #pragma unroll
    for (int c = 0; c < 3; ++c){
      float p = M[0][c] + v1*M[1][c] + v2*M[2][c];
      qmat[0*3+c] = M[0][c] - tau0*p;
      qmat[1*3+c] = M[1][c] - tau0*v1*p;
      qmat[2*3+c] = M[2][c] - tau0*v2*p;
    }
  }
}

__global__ __launch_bounds__(256) void xform_kernel(const float* __restrict__ pc,
    const float* __restrict__ q, float* __restrict__ x){
  int i = blockIdx.x*256 + threadIdx.x;
  if (i >= NP) return;
  float p0 = pc[i*3+0], p1 = pc[i*3+1], p2 = pc[i*3+2];
  x[i*3+0] = p0*q[0] + p1*q[3] + p2*q[6];
  x[i*3+1] = p0*q[1] + p1*q[4] + p2*q[7];
  x[i*3+2] = p0*q[2] + p1*q[5] + p2*q[8];
}

// ---------------- generic f32 GEMM (M x K @ K x ncols), 64x64 tiles ----------------
// STORE: write C; COLMAX: atomic col-max (encoded); BT: B is [ncols, K] row-major (B^T);
// D2EPI: out = bias[col] - 2*acc (distance-matrix epilogue, bias = col squared-norms)
template<int STORE, int COLMAX, int BT, int D2EPI>
__global__ __launch_bounds__(256) void gemm_kernel(
    const float* __restrict__ A, int lda,
    const float* __restrict__ B, int ldb,
    const float* __restrict__ bias,
    float* __restrict__ C, unsigned* __restrict__ cmax,
    int kloop, int kreal, int ncols, int remap_thresh, int remap_shift){
  __shared__ float As[32][68];
  __shared__ float Bs[32][68];
  int tid = threadIdx.x;
  int nbx = ncols >> 6;
  int bx = blockIdx.x % nbx, by = blockIdx.x / nbx;
  int tx = tid & 15, ty = tid >> 4;
  int row0 = by*64, col0 = bx*64;
  float acc[4][4];
  #pragma unroll
  for (int r = 0; r < 4; ++r)
    #pragma unroll
    for (int c = 0; c < 4; ++c) acc[r][c] = 0.f;

  for (int kt = 0; kt < kloop; kt += 32){
    // stage A (64 rows x 32 k), transposed into As[k][m]
    {
      int m = tid & 63, kq = tid >> 6;
      #pragma unroll
      for (int h = 0; h < 2; ++h){
        int k4 = kq + h*4;
        float4 av = make_float4(0.f,0.f,0.f,0.f);
        if (kt + k4*4 < kreal)
          av = *(const float4*)&A[(size_t)(row0+m)*lda + kt + k4*4];
        As[k4*4+0][m] = av.x; As[k4*4+1][m] = av.y;
        As[k4*4+2][m] = av.z; As[k4*4+3][m] = av.w;
      }
    }
    // stage B (32 k x 64 cols)
    if (BT){
      int c = tid & 63, kq = tid >> 6;
      #pragma unroll
      for (int h = 0; h < 2; ++h){
        int k4 = kq + h*4;
        float4 bv = make_float4(0.f,0.f,0.f,0.f);
        if (kt + k4*4 < kreal)
          bv = *(const float4*)&B[(size_t)(col0+c)*ldb + kt + k4*4];
        Bs[k4*4+0][c] = bv.x; Bs[k4*4+1][c] = bv.y;
        Bs[k4*4+2][c] = bv.z; Bs[k4*4+3][c] = bv.w;
      }
    } else {
      int k = tid & 31, cq = tid >> 5;
      #pragma unroll
      for (int h = 0; h < 2; ++h){
        int c4 = cq + h*8;
        int krow = kt + k;
        int brow = (krow >= remap_thresh) ? krow + remap_shift : krow;
        float4 bv = *(const float4*)&B[(size_t)brow*ldb + col0 + c4*4];
        *(float4*)&Bs[k][c4*4] = bv;
      }
    }
    __syncthreads();
    #pragma unroll
    for (int k = 0; k < 32; ++k){
      float4 a4 = *(const float4*)&As[k][ty*4];
      float4 b4 = *(const float4*)&Bs[k][tx*4];
      float av[4] = {a4.x, a4.y, a4.z, a4.w};
      float bv[4] = {b4.x, b4.y, b4.z, b4.w};
      #pragma unroll
      for (int r = 0; r < 4; ++r)
        #pragma unroll
        for (int c = 0; c < 4; ++c) acc[r][c] += av[r]*bv[c];
    }
    __syncthreads();
  }
  // epilogue
  float bvv[4];
  #pragma unroll
  for (int c = 0; c < 4; ++c) bvv[c] = bias[col0 + tx*4 + c];
  float val[4][4];
  #pragma unroll
  for (int r = 0; r < 4; ++r)
    #pragma unroll
    for (int c = 0; c < 4; ++c)
      val[r][c] = D2EPI ? (bvv[c] - 2.f*acc[r][c]) : (acc[r][c] + bvv[c]);
  if (STORE){
    #pragma unroll
    for (int r = 0; r < 4; ++r){
      float4 v = make_float4(val[r][0], val[r][1], val[r][2], val[r][3]);
      *(float4*)&C[(size_t)(row0 + ty*4 + r)*ncols + col0 + tx*4] = v;
    }
  }
  if (COLMAX){
    float cm[4];
    #pragma unroll
    for (int c = 0; c < 4; ++c)
      cm[c] = fmaxf(fmaxf(val[0][c], val[1][c]), fmaxf(val[2][c], val[3][c]));
    float* red = (float*)As;
    #pragma unroll
    for (int c = 0; c < 4; ++c) red[ty*64 + tx*4 + c] = cm[c];
    __syncthreads();
    if (tid < 64){
      float m = red[tid];
      #pragma unroll
      for (int t = 1; t < 16; ++t) m = fmaxf(m, red[t*64 + tid]);
      atomicMax(&cmax[col0 + tid], fenc(m));
    }
  }
}

// ---------------- top-k extraction (per-wave, row in LDS) ----------------
template<int K>
__device__ inline void extract_topk(float* d2row, int lane, int* __restrict__ nbr_row){
  float gmin[8]; int gidx[8];
  const int basej = lane*64;
  #pragma unroll
  for (int g = 0; g < 8; ++g){
    float mv = 3e38f; int mi = basej + g*8;
    #pragma unroll
    for (int e = 0; e < 8; ++e){
      int j = basej + g*8 + e;
      float v = d2row[j];
      bool c = v < mv; mv = c ? v : mv; mi = c ? j : mi;
    }
    gmin[g] = mv; gidx[g] = mi;
  }
  float lv; int li;
  {
    lv = gmin[0]; li = gidx[0];
    #pragma unroll
    for (int g = 1; g < 8; ++g){
      bool c = (gmin[g] < lv) || (gmin[g] == lv && gidx[g] < li);
      lv = c ? gmin[g] : lv; li = c ? gidx[g] : li;
    }
  }
  int keep = 0;
  for (int r = 0; r < K; ++r){
    float v = lv; int ix = li;
    #pragma unroll
    for (int off = 32; off; off >>= 1){
      float ov = __shfl_xor(v, off);
      int oi = __shfl_xor(ix, off);
      bool c = (ov < v) || (ov == v && oi < ix);
      v = c ? ov : v; ix = c ? oi : ix;
    }
    if (lane == r) keep = ix;
    if ((ix >> 6) == lane){
      d2row[ix] = 3e38f;
      int g = (ix >> 3) & 7;
      float mv = 3e38f; int mi = basej + g*8;
      #pragma unroll
      for (int e = 0; e < 8; ++e){
        int j = basej + g*8 + e;
        float vv = d2row[j];
        bool cc = vv < mv; mv = cc ? vv : mv; mi = cc ? j : mi;
      }
      #pragma unroll
      for (int g2 = 0; g2 < 8; ++g2){ if (g2 == g){ gmin[g2] = mv; gidx[g2] = mi; } }
      lv = gmin[0]; li = gidx[0];
      #pragma unroll
      for (int g = 1; g < 8; ++g){
        bool c = (gmin[g] < lv) || (gmin[g] == lv && gidx[g] < li);
        lv = c ? gmin[g] : lv; li = c ? gidx[g] : li;
      }
    }
  }
  if (lane < K) nbr_row[lane] = keep;
}

// kNN over 2-3 coordinate dims, fully fused (coords cached in LDS)
template<int D>
__global__ __launch_bounds__(256) void knn_small_kernel(const float* __restrict__ x,
    int dA, int dB, int dC, int* __restrict__ nbr){
  __shared__ float cs[D][NP];
  __shared__ float d2row[4][NP];
  int tid = threadIdx.x, lane = tid & 63, w = tid >> 6;
  for (int j = tid; j < NP; j += 256){
    cs[0][j] = x[j*3 + dA];
    cs[1][j] = x[j*3 + dB];
    if (D == 3) cs[2][j] = x[j*3 + dC];
  }
  __syncthreads();
  int i = blockIdx.x*4 + w;
  float xi[D];
  xi[0] = x[i*3 + dA]; xi[1] = x[i*3 + dB];
  if (D == 3) xi[2] = x[i*3 + dC];
  for (int jc = 0; jc < 64; ++jc){
    int j = jc*64 + lane;
    float sq = 0.f, dot = 0.f;
    #pragma unroll
    for (int c = 0; c < D; ++c){ float v = cs[c][j]; sq += v*v; dot += v*xi[c]; }
    d2row[w][j] = sq - 2.f*dot;   // sq_i dropped: rank-invariant shift
  }
  extract_topk<20>(&d2row[w][0], lane, &nbr[i*20]);
}

// top-k from a precomputed (chunked) d2 matrix
template<int K>
__global__ __launch_bounds__(256) void topk_kernel(const float* __restrict__ d2m,
    int* __restrict__ nbr_chunk){
  __shared__ float d2row[4][NP];
  int tid = threadIdx.x, lane = tid & 63, w = tid >> 6;
  int il = blockIdx.x*4 + w;
  #pragma unroll
  for (int h = 0; h < 16; ++h){
    int j4 = lane + h*64;
    float4 v = *(const float4*)&d2m[(size_t)il*NP + j4*4];
    *(float4*)&d2row[w][j4*4] = v;
  }
  extract_topk<K>(&d2row[w][0], lane, &nbr_chunk[il*K]);
}

// ---------------- graph utilities ----------------
__global__ __launch_bounds__(256) void sq_kernel(const float* __restrict__ f, int ld, int D,
    float* __restrict__ sq){
  int i = blockIdx.x*256 + threadIdx.x;
  if (i >= NP) return;
  float s = 0.f;
  for (int c = 0; c < D; ++c){ float v = f[(size_t)i*ld + c]; s += v*v; }
  sq[i] = s;
}

__global__ __launch_bounds__(256) void deg_kernel(const int* __restrict__ nbr, int total,
    int* __restrict__ deg){
  int e = blockIdx.x*256 + threadIdx.x;
  if (e < total) atomicAdd(&deg[nbr[e]], 1);
}

// DGL GraphConv norm='both': out[i] = ((1/sqrt(k)) * sum_j x[j]/sqrt(deg_j)) @ W + b
template<int DIN, int DOUT>
__global__ __launch_bounds__(256) void gc_kernel(const int* __restrict__ nbr, int k, float kscale,
    const int* __restrict__ deg, const float* __restrict__ x, int ldx,
    const float* __restrict__ w, const float* __restrict__ b,
    float* __restrict__ out, int ldo){
  __shared__ float aggs[4][DIN];
  int tid = threadIdx.x, lane = tid & 63, wv = tid >> 6;
  int i = blockIdx.x*4 + wv;
  if (lane < DIN){
    float agg = 0.f;
    for (int j = 0; j < k; ++j){
      int idx = nbr[i*k + j];
      float rs = rsqrtf(fmaxf((float)deg[idx], 1.0f));
      agg += x[(size_t)idx*ldx + lane] * rs;
    }
    aggs[wv][lane] = agg * kscale;
  }
  __syncthreads();
  if (lane < DOUT){
    float o = b[lane];
    #pragma unroll 8
    for (int d = 0; d < DIN; ++d) o += aggs[wv][d] * w[d*DOUT + lane];
    out[(size_t)i*ldo + lane] = o;
  }
}

// ---------------- GAT pieces ----------------
__global__ __launch_bounds__(256) void crow_kernel(const unsigned* __restrict__ fc0max,
    const float* __restrict__ ws_, const float* __restrict__ wd_,
    float* __restrict__ c_s, float* __restrict__ c_d){
  __shared__ float hr[1024];
  int col = (blockIdx.x >> 1)*256 + threadIdx.x;
  const float* W = (blockIdx.x & 1) ? wd_ : ws_;
  float* outp = (blockIdx.x & 1) ? c_d : c_s;
  for (int j = threadIdx.x; j < 1024; j += 256) hr[j] = fdec(fc0max[j]);
  __syncthreads();
  float acc = 0.f;
  for (int d = 0; d < 1024; ++d) acc += hr[d]*W[(size_t)(192+d)*1024 + col];
  outp[col] = acc;
}

// GATv2, restructured for latency hiding:
//   grid NP/4 blocks; 4 waves/block = 4 heads; 4 nodes iterated per block.
//   All 20 neighbor rows loaded in two batches of 10 float4 loads in flight;
//   batch-merged online softmax (mathematically = sequential online softmax).
__global__ __launch_bounds__(256) void gat_kernel(const int* __restrict__ nbr,
    const float* __restrict__ fs, const float* __restrict__ fd,
    const float* __restrict__ a, unsigned* __restrict__ gmax){
  int tid = threadIdx.x, lane = tid & 63, h = tid >> 6;
  float4 at = *(const float4*)&a[h*256 + lane*4];
  float av[4] = {at.x, at.y, at.z, at.w};
  float runmax[4] = {-3e38f, -3e38f, -3e38f, -3e38f};
  for (int it = 0; it < 4; ++it){
    int i = blockIdx.x*4 + it;
    float4 fdv4 = *(const float4*)&fd[(size_t)i*1024 + h*256 + lane*4];
    float fdv[4] = {fdv4.x, fdv4.y, fdv4.z, fdv4.w};
    int nb[20];
    #pragma unroll
    for (int j = 0; j < 20; ++j) nb[j] = nbr[i*20 + j];
    float m = -3e38f, l = 0.f;
    float o[4] = {0.f, 0.f, 0.f, 0.f};
    #pragma unroll
    for (int half = 0; half < 2; ++half){
      float4 fv[10];
      #pragma unroll
      for (int j = 0; j < 10; ++j)
        fv[j] = *(const float4*)&fs[(size_t)nb[half*10 + j]*1024 + h*256 + lane*4];
      float p[10];
      #pragma unroll
      for (int j = 0; j < 10; ++j){
        float e0 = fv[j].x + fdv[0]; e0 = (e0 > 0.f) ? e0 : 0.2f*e0;
        float e1 = fv[j].y + fdv[1]; e1 = (e1 > 0.f) ? e1 : 0.2f*e1;
        float e2 = fv[j].z + fdv[2]; e2 = (e2 > 0.f) ? e2 : 0.2f*e2;
        float e3 = fv[j].w + fdv[3]; e3 = (e3 > 0.f) ? e3 : 0.2f*e3;
        p[j] = e0*av[0] + e1*av[1] + e2*av[2] + e3*av[3];
      }
      #pragma unroll
      for (int off = 32; off; off >>= 1){
        #pragma unroll
        for (int j = 0; j < 10; ++j) p[j] += __shfl_xor(p[j], off);
      }
      float bm = p[0];
      #pragma unroll
      for (int j = 1; j < 10; ++j) bm = fmaxf(bm, p[j]);
      float mn = fmaxf(m, bm);
      float scale = __expf(m - mn);
      l *= scale;
      #pragma unroll
      for (int c = 0; c < 4; ++c) o[c] *= scale;
      #pragma unroll
      for (int j = 0; j < 10; ++j){
        float wj = __expf(p[j] - mn);
        l += wj;
        o[0] += wj*fv[j].x; o[1] += wj*fv[j].y;
        o[2] += wj*fv[j].z; o[3] += wj*fv[j].w;
      }
      m = mn;
    }
    float inv = 1.f/l;
    #pragma unroll
    for (int c = 0; c < 4; ++c) runmax[c] = fmaxf(runmax[c], o[c]*inv);
  }
  #pragma unroll
  for (int c = 0; c < 4; ++c) atomicMax(&gmax[h*256 + lane*4 + c], fenc(runmax[c]));
}

__global__ __launch_bounds__(256) void head_kernel(const unsigned* __restrict__ gmax,
    const float* __restrict__ gb, const float* __restrict__ w1, const float* __restrict__ b1,
    const float* __restrict__ w2, const float* __restrict__ b2,
    const float* __restrict__ w3, const float* __restrict__ b3, float* __restrict__ out){
  __shared__ float hm[1024];
  __shared__ float s1[256];
  __shared__ float s2[64];
  int tid = threadIdx.x;
  for (int j = tid; j < 1024; j += 256) hm[j] = fdec(gmax[j]) + gb[j];
  __syncthreads();
  float acc = b1[tid];
  for (int d = 0; d < 1024; ++d) acc += hm[d]*w1[d*256+tid];
  s1[tid] = fmaxf(acc, 0.f);
  __syncthreads();
  if (tid < 64){
    float a2 = b2[tid];
    for (int d = 0; d < 256; ++d) a2 += s1[d]*w2[d*64+tid];
    s2[tid] = fmaxf(a2, 0.f);
  }
  __syncthreads();
  if (tid < 40){
    float a3 = b3[tid];
    for (int d = 0; d < 64; ++d) a3 += s2[d]*w3[d*40+tid];
    out[tid] = a3;
  }
}

// ---------------- launch ----------------
extern "C" void kernel_launch(void* const* d_in, const int* in_sizes, int n_in,
                              void* d_out, int out_size, void* d_ws, size_t ws_size,
                              hipStream_t stream){
  (void)in_sizes; (void)n_in; (void)out_size; (void)ws_size;
  const float* pc    = (const float*)d_in[0];
  const float* t_w1  = (const float*)d_in[1];
  const float* t_b1  = (const float*)d_in[2];
  const float* t_w2  = (const float*)d_in[3];
  const float* t_b2  = (const float*)d_in[4];
  const float* t_w3  = (const float*)d_in[5];
  const float* t_b3  = (const float*)d_in[6];
  const float* t_w4  = (const float*)d_in[7];
  const float* t_b4  = (const float*)d_in[8];
  const float* gc1_w = (const float*)d_in[9];
  const float* gc1_b = (const float*)d_in[10];
  const float* gc_w  = (const float*)d_in[11];
  const float* gc_b  = (const float*)d_in[12];
  const float* gp1_w = (const float*)d_in[13];
  const float* gp1_b = (const float*)d_in[14];
  const float* gp2_w = (const float*)d_in[15];
  const float* gp2_b = (const float*)d_in[16];
  const float* fc0_w = (const float*)d_in[17];
  const float* fc0_b = (const float*)d_in[18];
  const float* gat_ws= (const float*)d_in[19];
  const float* gat_wd= (const float*)d_in[20];
  const float* gat_a = (const float*)d_in[21];
  const float* gat_b = (const float*)d_in[22];
  const float* fc1_w = (const float*)d_in[23];
  const float* fc1_b = (const float*)d_in[24];
  const float* fc2_w = (const float*)d_in[25];
  const float* fc2_b = (const float*)d_in[26];
  const float* fc3_w = (const float*)d_in[27];
  const float* fc3_b = (const float*)d_in[28];
  float* out = (float*)d_out;

  char* basep = (char*)d_ws; size_t off = 0;
  auto alloc = [&](size_t bytes)->void*{
    void* p = basep + off; off += (bytes + 255) & ~(size_t)255; return p;
  };
  float* t1      = (float*)alloc((size_t)NP*64*4);
  float* x       = (float*)alloc((size_t)NP*3*4);
  float* qmat    = (float*)alloc(64);
  unsigned* tpool  = (unsigned*)alloc(1024*4);
  unsigned* fc0max = (unsigned*)alloc(1024*4);
  unsigned* gatmax = (unsigned*)alloc(1024*4);
  float* c_s     = (float*)alloc(1024*4);
  float* c_d     = (float*)alloc(1024*4);
  float* tmp64   = (float*)alloc((size_t)NP*64*4);
  float* hfull   = (float*)alloc((size_t)NP*384*4);
  float* hp0     = (float*)alloc((size_t)NP*16*4);
  float* hp1     = (float*)alloc((size_t)NP*16*4);
  float* hp2     = (float*)alloc((size_t)NP*16*4);
  float* sqbuf   = (float*)alloc((size_t)NP*4);
  float* d2c     = (float*)alloc((size_t)2048*NP*4);   // 32 MB: 2048-row chunks
  int* nbr_g0    = (int*)alloc((size_t)NP*20*4);
  int* nbr_gxy   = (int*)alloc((size_t)NP*20*4);
  int* nbr_gyz   = (int*)alloc((size_t)NP*20*4);
  int* nbr_gxz   = (int*)alloc((size_t)NP*20*4);
  int* nbr_gf0   = (int*)alloc((size_t)NP*20*4);
  int* nbr_gf1   = (int*)alloc((size_t)NP*20*4);
  int* nbr_gp0   = (int*)alloc((size_t)NP*50*4);
  int* nbr_gp1   = (int*)alloc((size_t)NP*50*4);
  int* nbr_gp2   = (int*)alloc((size_t)NP*50*4);
  int* degs      = (int*)alloc((size_t)9*NP*4);
  float* fsb     = (float*)alloc((size_t)NP*1024*4);
  float* fdb     = (float*)alloc((size_t)NP*1024*4);

  const float KS20 = 0.22360679774997896f;   // 1/sqrt(20)
  const float KS50 = 0.14142135623730950f;   // 1/sqrt(50)
  const int NOMAP = 1 << 30;

  hipMemsetAsync(tpool,  0, 1024*4, stream);
  hipMemsetAsync(fc0max, 0, 1024*4, stream);
  hipMemsetAsync(gatmax, 0, 1024*4, stream);
  hipMemsetAsync(degs,   0, (size_t)9*NP*4, stream);

  // ---- T-net ----
  t1_kernel<<<NP/4, 256, 0, stream>>>(pc, t_w1, t_b1, t1);
  gemm_kernel<0,1,0,0><<<16*64, 256, 0, stream>>>(t1, 64, t_w2, 1024, t_b2,
      nullptr, tpool, 64, 64, 1024, NOMAP, 0);
  tnet_tail_kernel<<<1, 256, 0, stream>>>(tpool, t_w3, t_b3, t_w4, t_b4, qmat, out + 40);
  xform_kernel<<<16, 256, 0, stream>>>(pc, qmat, x);

  // ---- coordinate kNN graphs ----
  knn_small_kernel<3><<<NP/4, 256, 0, stream>>>(x, 0, 1, 2, nbr_g0);
  knn_small_kernel<2><<<NP/4, 256, 0, stream>>>(x, 0, 1, 0, nbr_gxy);
  knn_small_kernel<2><<<NP/4, 256, 0, stream>>>(x, 1, 2, 0, nbr_gyz);
  knn_small_kernel<2><<<NP/4, 256, 0, stream>>>(x, 0, 2, 0, nbr_gxz);
  deg_kernel<<<(NP*20+255)/256, 256, 0, stream>>>(nbr_g0,  NP*20, degs + 0*NP);
  deg_kernel<<<(NP*20+255)/256, 256, 0, stream>>>(nbr_gxy, NP*20, degs + 1*NP);
  deg_kernel<<<(NP*20+255)/256, 256, 0, stream>>>(nbr_gyz, NP*20, degs + 2*NP);
  deg_kernel<<<(NP*20+255)/256, 256, 0, stream>>>(nbr_gxz, NP*20, degs + 3*NP);

  // ---- main branch ----
  gc_kernel<3,64><<<NP/4, 256, 0, stream>>>(nbr_g0, 20, KS20, degs + 0*NP, x, 3,
      gc1_w, gc1_b, tmp64, 64);
  gc_kernel<64,64><<<NP/4, 256, 0, stream>>>(nbr_g0, 20, KS20, degs + 0*NP, tmp64, 64,
      gc_w + 0*4096, gc_b + 0*64, hfull + 0, 384);
  // gf0 = knn(h0, 20)  — 2048-row chunks
  sq_kernel<<<16, 256, 0, stream>>>(hfull + 0, 384, 64, sqbuf);
  for (int ch = 0; ch < 2; ++ch){
    gemm_kernel<1,0,1,1><<<32*64, 256, 0, stream>>>(hfull + (size_t)ch*2048*384, 384,
        hfull + 0, 384, sqbuf, d2c, nullptr, 64, 64, NP, NOMAP, 0);
    topk_kernel<20><<<512, 256, 0, stream>>>(d2c, nbr_gf0 + ch*2048*20);
  }
  deg_kernel<<<(NP*20+255)/256, 256, 0, stream>>>(nbr_gf0, NP*20, degs + 4*NP);
  gc_kernel<64,64><<<NP/4, 256, 0, stream>>>(nbr_gf0, 20, KS20, degs + 4*NP, hfull + 0, 384,
      gc_w + 1*4096, gc_b + 1*64, tmp64, 64);
  gc_kernel<64,64><<<NP/4, 256, 0, stream>>>(nbr_gf0, 20, KS20, degs + 4*NP, tmp64, 64,
      gc_w + 2*4096, gc_b + 2*64, hfull + 64, 384);
  // gf1 = knn(h1, 20)
  sq_kernel<<<16, 256, 0, stream>>>(hfull + 64, 384, 64, sqbuf);
  for (int ch = 0; ch < 2; ++ch){
    gemm_kernel<1,0,1,1><<<32*64, 256, 0, stream>>>(hfull + 64 + (size_t)ch*2048*384, 384,
        hfull + 64, 384, sqbuf, d2c, nullptr, 64, 64, NP, NOMAP, 0);
    topk_kernel<20><<<512, 256, 0, stream>>>(d2c, nbr_gf1 + ch*2048*20);
  }
  deg_kernel<<<(NP*20+255)/256, 256, 0, stream>>>(nbr_gf1, NP*20, degs + 5*NP);
  gc_kernel<64,64><<<NP/4, 256, 0, stream>>>(nbr_gf1, 20, KS20, degs + 5*NP, hfull + 64, 384,
      gc_w + 3*4096, gc_b + 3*64, hfull + 128, 384);

  // ---- plane branches ----
  int* nbr_pl[3] = {nbr_gxy, nbr_gyz, nbr_gxz};
  int* nbr_gp[3] = {nbr_gp0, nbr_gp1, nbr_gp2};
  float* hps[3]  = {hp0, hp1, hp2};
  for (int i = 0; i < 3; ++i){
    gc_kernel<3,16><<<NP/4, 256, 0, stream>>>(nbr_pl[i], 20, KS20, degs + (1+i)*NP, x, 3,
        gp1_w + i*48, gp1_b + i*16, hps[i], 16);
    sq_kernel<<<16, 256, 0, stream>>>(hps[i], 16, 16, sqbuf);
    for (int ch = 0; ch < 2; ++ch){
      gemm_kernel<1,0,1,1><<<32*64, 256, 0, stream>>>(hps[i] + (size_t)ch*2048*16, 16,
          hps[i], 16, sqbuf, d2c, nullptr, 32, 16, NP, NOMAP, 0);
      topk_kernel<50><<<512, 256, 0, stream>>>(d2c, nbr_gp[i] + ch*2048*50);
    }
    deg_kernel<<<(NP*50+255)/256, 256, 0, stream>>>(nbr_gp[i], NP*50, degs + (6+i)*NP);
    gc_kernel<16,64><<<NP/4, 256, 0, stream>>>(nbr_gp[i], 50, KS50, degs + (6+i)*NP,
        hps[i], 16, gp2_w + i*1024, gp2_b + i*64, hfull + 192 + 64*i, 384);
  }

  // ---- fc0 + max, then fs/fd GEMMs with h_ folded in as a per-column constant ----
  gemm_kernel<0,1,0,0><<<16*64, 256, 0, stream>>>(hfull, 384, fc0_w, 1024, fc0_b,
      nullptr, fc0max, 192, 192, 1024, NOMAP, 0);
  crow_kernel<<<8, 256, 0, stream>>>(fc0max, gat_ws, gat_wd, c_s, c_d);
  gemm_kernel<1,0,0,0><<<16*64, 256, 0, stream>>>(hfull, 384, gat_ws, 1024, c_s,
      fsb, nullptr, 384, 384, 1024, 192, 1024);
  gemm_kernel<1,0,0,0><<<16*64, 256, 0, stream>>>(hfull, 384, gat_wd, 1024, c_d,
      fdb, nullptr, 384, 384, 1024, 192, 1024);

  // ---- GATv2 + head ----
  gat_kernel<<<NP/4, 256, 0, stream>>>(nbr_g0, fsb, fdb, gat_a, gatmax);
  head_kernel<<<1, 256, 0, stream>>>(gatmax, gat_b, fc1_w, fc1_b, fc2_w, fc2_b,
      fc3_w, fc3_b, out);
}

// Round 8
// 1433.309 us; speedup vs baseline: 1.6222x; 1.2931x over previous
//
#include <hip/hip_runtime.h>
#include <math.h>

#define NP 4096

// ---------------- helpers ----------------
__device__ inline unsigned fenc(float f){
  unsigned b = __float_as_uint(f);
  return (b & 0x80000000u) ? ~b : (b | 0x80000000u);
}
__device__ inline float fdec(unsigned u){
  return (u & 0x80000000u) ? __uint_as_float(u ^ 0x80000000u) : __uint_as_float(~u);
}

// ---------------- T-net ----------------
__global__ __launch_bounds__(256) void t1_kernel(const float* __restrict__ pc,
    const float* __restrict__ w1, const float* __restrict__ b1, float* __restrict__ t1){
  int i = blockIdx.x*4 + (threadIdx.x>>6);
  int o = threadIdx.x & 63;
  float p0 = pc[i*3+0], p1 = pc[i*3+1], p2 = pc[i*3+2];
  float v = p0*w1[o] + p1*w1[64+o] + p2*w1[128+o] + b1[o];
  t1[i*64+o] = fmaxf(v, 0.f);
}

__global__ __launch_bounds__(256) void tnet_tail_kernel(const unsigned* __restrict__ tpool,
    const float* __restrict__ w3, const float* __restrict__ b3,
    const float* __restrict__ w4, const float* __restrict__ b4,
    float* __restrict__ qmat, float* __restrict__ rout){
  __shared__ float tp[1024];
  __shared__ float t3[256];
  __shared__ float t4[9];
  int tid = threadIdx.x;
  for (int j = tid; j < 1024; j += 256) tp[j] = fdec(tpool[j]);
  __syncthreads();
  float acc = b3[tid];
  for (int d = 0; d < 1024; ++d) acc += tp[d]*w3[d*256+tid];
  t3[tid] = fmaxf(acc, 0.f);
  __syncthreads();
  if (tid < 9){
    float a = b4[tid];
    for (int d = 0; d < 256; ++d) a += t3[d]*w4[d*9+tid];
    t4[tid] = a;
  }
  __syncthreads();
  if (tid == 0){
    float a00=t4[0], a01=t4[1], a02=t4[2];
    float a10=t4[3], a11=t4[4], a12=t4[5];
    float a20=t4[6], a21=t4[7], a22=t4[8];
    // Householder QR, LAPACK sign convention (beta = -sign(alpha)*norm)
    float tau0 = 0.f, v1 = 0.f, v2 = 0.f;
    float xn2 = a10*a10 + a20*a20;
    if (xn2 > 0.f){
      float alpha = a00;
      float nrm = sqrtf(alpha*alpha + xn2);
      float beta = (alpha >= 0.f) ? -nrm : nrm;
      tau0 = (beta - alpha)/beta;
      float inv = 1.f/(alpha - beta);
      v1 = a10*inv; v2 = a20*inv;
      float s1 = a01 + v1*a11 + v2*a21; s1 *= tau0;
      a01 -= s1; a11 -= v1*s1; a21 -= v2*s1;
      float s2 = a02 + v1*a12 + v2*a22; s2 *= tau0;
      a02 -= s2; a12 -= v1*s2; a22 -= v2*s2;
      a00 = beta;
    }
    float tau1 = 0.f, wv = 0.f;
    float xn1 = a21*a21;
    if (xn1 > 0.f){
      float alpha = a11;
      float nrm = sqrtf(alpha*alpha + xn1);
      float beta = (alpha >= 0.f) ? -nrm : nrm;
      tau1 = (beta - alpha)/beta;
      wv = a21/(alpha - beta);
      float s = a12 + wv*a22; s *= tau1;
      a12 -= s; a22 -= wv*s;
      a11 = beta;
    }
    rout[0]=a00; rout[1]=a01; rout[2]=a02;
    rout[3]=0.f; rout[4]=a11; rout[5]=a12;
    rout[6]=0.f; rout[7]=0.f; rout[8]=a22;
    // Q = H0 * H1
    float M[3][3] = {{1,0,0},{0,1,0},{0,0,1}};
    M[1][1] -= tau1;     M[1][2] -= tau1*wv;
    M[2][1] -= tau1*wv;  M[2][2] -= tau1*wv*wv;
    #pragma unroll
    for (int c = 0; c < 3; ++c){
      float p = M[0][c] + v1*M[1][c] + v2*M[2][c];
      qmat[0*3+c] = M[0][c] - tau0*p;
      qmat[1*3+c] = M[1][c] - tau0*v1*p;
      qmat[2*3+c] = M[2][c] - tau0*v2*p;
    }
  }
}

__global__ __launch_bounds__(256) void xform_kernel(const float* __restrict__ pc,
    const float* __restrict__ q, float* __restrict__ x){
  int i = blockIdx.x*256 + threadIdx.x;
  if (i >= NP) return;
  float p0 = pc[i*3+0], p1 = pc[i*3+1], p2 = pc[i*3+2];
  x[i*3+0] = p0*q[0] + p1*q[3] + p2*q[6];
  x[i*3+1] = p0*q[1] + p1*q[4] + p2*q[7];
  x[i*3+2] = p0*q[2] + p1*q[5] + p2*q[8];
}

// pack transformed coords into coalescing-friendly layouts (L2-resident)
__global__ __launch_bounds__(256) void pack_kernel(const float* __restrict__ x,
    float4* __restrict__ p3, float2* __restrict__ pxy,
    float2* __restrict__ pyz, float2* __restrict__ pxz){
  int i = blockIdx.x*256 + threadIdx.x;
  if (i >= NP) return;
  float a = x[i*3], b = x[i*3+1], c = x[i*3+2];
  p3[i]  = make_float4(a, b, c, 0.f);
  pxy[i] = make_float2(a, b);
  pyz[i] = make_float2(b, c);
  pxz[i] = make_float2(a, c);
}

// ---------------- generic f32 GEMM (M x K @ K x ncols), 64x64 tiles ----------------
template<int STORE, int COLMAX, int BT, int D2EPI>
__global__ __launch_bounds__(256) void gemm_kernel(
    const float* __restrict__ A, int lda,
    const float* __restrict__ B, int ldb,
    const float* __restrict__ bias,
    float* __restrict__ C, unsigned* __restrict__ cmax,
    int kloop, int kreal, int ncols, int remap_thresh, int remap_shift){
  __shared__ float As[32][68];
  __shared__ float Bs[32][68];
  int tid = threadIdx.x;
  int nbx = ncols >> 6;
  int bx = blockIdx.x % nbx, by = blockIdx.x / nbx;
  int tx = tid & 15, ty = tid >> 4;
  int row0 = by*64, col0 = bx*64;
  float acc[4][4];
  #pragma unroll
  for (int r = 0; r < 4; ++r)
    #pragma unroll
    for (int c = 0; c < 4; ++c) acc[r][c] = 0.f;

  for (int kt = 0; kt < kloop; kt += 32){
    {
      int m = tid & 63, kq = tid >> 6;
      #pragma unroll
      for (int h = 0; h < 2; ++h){
        int k4 = kq + h*4;
        float4 av = make_float4(0.f,0.f,0.f,0.f);
        if (kt + k4*4 < kreal)
          av = *(const float4*)&A[(size_t)(row0+m)*lda + kt + k4*4];
        As[k4*4+0][m] = av.x; As[k4*4+1][m] = av.y;
        As[k4*4+2][m] = av.z; As[k4*4+3][m] = av.w;
      }
    }
    if (BT){
      int c = tid & 63, kq = tid >> 6;
      #pragma unroll
      for (int h = 0; h < 2; ++h){
        int k4 = kq + h*4;
        float4 bv = make_float4(0.f,0.f,0.f,0.f);
        if (kt + k4*4 < kreal)
          bv = *(const float4*)&B[(size_t)(col0+c)*ldb + kt + k4*4];
        Bs[k4*4+0][c] = bv.x; Bs[k4*4+1][c] = bv.y;
        Bs[k4*4+2][c] = bv.z; Bs[k4*4+3][c] = bv.w;
      }
    } else {
      int k = tid & 31, cq = tid >> 5;
      #pragma unroll
      for (int h = 0; h < 2; ++h){
        int c4 = cq + h*8;
        int krow = kt + k;
        int brow = (krow >= remap_thresh) ? krow + remap_shift : krow;
        float4 bv = *(const float4*)&B[(size_t)brow*ldb + col0 + c4*4];
        *(float4*)&Bs[k][c4*4] = bv;
      }
    }
    __syncthreads();
    #pragma unroll
    for (int k = 0; k < 32; ++k){
      float4 a4 = *(const float4*)&As[k][ty*4];
      float4 b4 = *(const float4*)&Bs[k][tx*4];
      float av[4] = {a4.x, a4.y, a4.z, a4.w};
      float bv[4] = {b4.x, b4.y, b4.z, b4.w};
      #pragma unroll
      for (int r = 0; r < 4; ++r)
        #pragma unroll
        for (int c = 0; c < 4; ++c) acc[r][c] += av[r]*bv[c];
    }
    __syncthreads();
  }
  float bvv[4];
  #pragma unroll
  for (int c = 0; c < 4; ++c) bvv[c] = bias[col0 + tx*4 + c];
  float val[4][4];
  #pragma unroll
  for (int r = 0; r < 4; ++r)
    #pragma unroll
    for (int c = 0; c < 4; ++c)
      val[r][c] = D2EPI ? (bvv[c] - 2.f*acc[r][c]) : (acc[r][c] + bvv[c]);
  if (STORE){
    #pragma unroll
    for (int r = 0; r < 4; ++r){
      float4 v = make_float4(val[r][0], val[r][1], val[r][2], val[r][3]);
      *(float4*)&C[(size_t)(row0 + ty*4 + r)*ncols + col0 + tx*4] = v;
    }
  }
  if (COLMAX){
    float cm[4];
    #pragma unroll
    for (int c = 0; c < 4; ++c)
      cm[c] = fmaxf(fmaxf(val[0][c], val[1][c]), fmaxf(val[2][c], val[3][c]));
    float* red = (float*)As;
    #pragma unroll
    for (int c = 0; c < 4; ++c) red[ty*64 + tx*4 + c] = cm[c];
    __syncthreads();
    if (tid < 64){
      float m = red[tid];
      #pragma unroll
      for (int t = 1; t < 16; ++t) m = fmaxf(m, red[t*64 + tid]);
      atomicMax(&cmax[col0 + tid], fenc(m));
    }
  }
}

// ---------------- top-k extraction, conflict-free ownership ----------------
// lane L owns slots j with (j&63)==L -> every LDS access is 64 consecutive
// floats per wave instruction (2 lanes/bank = free).
template<int K>
__device__ inline void extract_topk(float* d2row, int lane, int* __restrict__ nbr_row){
  float gmin[8]; int gidx[8];
  #pragma unroll
  for (int g = 0; g < 8; ++g){
    float mv = 3e38f; int mi = g*512 + lane;
    #pragma unroll
    for (int e = 0; e < 8; ++e){
      int j = (g*8 + e)*64 + lane;
      float v = d2row[j];
      bool c = v < mv; mv = c ? v : mv; mi = c ? j : mi;
    }
    gmin[g] = mv; gidx[g] = mi;
  }
  float lv; int li;
  lv = gmin[0]; li = gidx[0];
  #pragma unroll
  for (int g = 1; g < 8; ++g){
    bool c = (gmin[g] < lv) || (gmin[g] == lv && gidx[g] < li);
    lv = c ? gmin[g] : lv; li = c ? gidx[g] : li;
  }
  int keep = 0;
  for (int r = 0; r < K; ++r){
    float v = lv; int ix = li;
    #pragma unroll
    for (int off = 32; off; off >>= 1){
      float ov = __shfl_xor(v, off);
      int oi = __shfl_xor(ix, off);
      bool c = (ov < v) || (ov == v && oi < ix);
      v = c ? ov : v; ix = c ? oi : ix;
    }
    if (lane == r) keep = ix;
    if ((ix & 63) == lane){
      d2row[ix] = 3e38f;
      int g = ix >> 9;
      float mv = 3e38f; int mi = g*512 + lane;
      #pragma unroll
      for (int e = 0; e < 8; ++e){
        int j = (g*8 + e)*64 + lane;
        float vv = d2row[j];
        bool cc = vv < mv; mv = cc ? vv : mv; mi = cc ? j : mi;
      }
      #pragma unroll
      for (int g2 = 0; g2 < 8; ++g2){ if (g2 == g){ gmin[g2] = mv; gidx[g2] = mi; } }
      lv = gmin[0]; li = gidx[0];
      #pragma unroll
      for (int g = 1; g < 8; ++g){
        bool c = (gmin[g] < lv) || (gmin[g] == lv && gidx[g] < li);
        lv = c ? gmin[g] : lv; li = c ? gidx[g] : li;
      }
    }
  }
  if (lane < K) nbr_row[lane] = keep;
}

// all 4 coordinate kNN graphs in one launch; packed coords from L2, LDS 64KB
__global__ __launch_bounds__(256) void knn_coord_kernel(const float4* __restrict__ p3,
    const float2* __restrict__ pxy, const float2* __restrict__ pyz,
    const float2* __restrict__ pxz, int* __restrict__ nbr4){
  __shared__ float d2row[4][NP];
  int tid = threadIdx.x, lane = tid & 63, w = tid >> 6;
  int gsel = blockIdx.x >> 10;
  int i = (blockIdx.x & 1023)*4 + w;
  float* dr = &d2row[w][0];
  if (gsel == 0){
    float4 q = p3[i];
    for (int jc = 0; jc < 64; ++jc){
      int j = jc*64 + lane;
      float4 p = p3[j];
      dr[j] = (p.x*p.x + p.y*p.y + p.z*p.z) - 2.f*(p.x*q.x + p.y*q.y + p.z*q.z);
    }
  } else {
    const float2* pp = (gsel == 1) ? pxy : (gsel == 2) ? pyz : pxz;
    float2 q = pp[i];
    for (int jc = 0; jc < 64; ++jc){
      int j = jc*64 + lane;
      float2 p = pp[j];
      dr[j] = (p.x*p.x + p.y*p.y) - 2.f*(p.x*q.x + p.y*q.y);
    }
  }
  extract_topk<20>(dr, lane, &nbr4[(size_t)gsel*NP*20 + i*20]);
}

// top-k from a precomputed (chunked) d2 matrix
template<int K>
__global__ __launch_bounds__(256) void topk_kernel(const float* __restrict__ d2m,
    int* __restrict__ nbr_chunk){
  __shared__ float d2row[4][NP];
  int tid = threadIdx.x, lane = tid & 63, w = tid >> 6;
  int il = blockIdx.x*4 + w;
  #pragma unroll
  for (int h = 0; h < 16; ++h){
    int j4 = lane + h*64;
    float4 v = *(const float4*)&d2m[(size_t)il*NP + j4*4];
    *(float4*)&d2row[w][j4*4] = v;
  }
  extract_topk<K>(&d2row[w][0], lane, &nbr_chunk[il*K]);
}

// ---------------- graph utilities ----------------
__global__ __launch_bounds__(256) void sq_kernel(const float* __restrict__ f, int ld, int D,
    float* __restrict__ sq){
  int i = blockIdx.x*256 + threadIdx.x;
  if (i >= NP) return;
  float s = 0.f;
  for (int c = 0; c < D; c += 4){
    float4 v = *(const float4*)&f[(size_t)i*ld + c];
    s += v.x*v.x + v.y*v.y + v.z*v.z + v.w*v.w;
  }
  sq[i] = s;
}

__global__ __launch_bounds__(256) void deg_kernel(const int* __restrict__ nbr, int total,
    int* __restrict__ deg){
  int e = blockIdx.x*256 + threadIdx.x;
  if (e < total) atomicAdd(&deg[nbr[e]], 1);
}

// degree counting for the 4 coordinate graphs in one launch
__global__ __launch_bounds__(256) void deg4_kernel(const int* __restrict__ nbr4,
    int* __restrict__ degs){
  int e = blockIdx.x*256 + threadIdx.x;
  int g = e / (NP*20);
  atomicAdd(&degs[g*NP + nbr4[e]], 1);
}

// DGL GraphConv norm='both', neighbor count templated; gathers batched 10-deep
template<int DIN, int DOUT, int KNB>
__global__ __launch_bounds__(256) void gc_kernel(const int* __restrict__ nbr, float kscale,
    const int* __restrict__ deg, const float* __restrict__ x, int ldx,
    const float* __restrict__ w, const float* __restrict__ b,
    float* __restrict__ out, int ldo){
  __shared__ float aggs[4][DIN];
  int tid = threadIdx.x, lane = tid & 63, wv = tid >> 6;
  int i = blockIdx.x*4 + wv;
  if (lane < DIN){
    float agg = 0.f;
    constexpr int CH = (KNB % 10 == 0) ? 10 : KNB;
    #pragma unroll
    for (int jj = 0; jj < KNB; jj += CH){
      int idx[CH]; float dv[CH]; float xv[CH];
      #pragma unroll
      for (int j = 0; j < CH; ++j) idx[j] = nbr[i*KNB + jj + j];
      #pragma unroll
      for (int j = 0; j < CH; ++j) dv[j] = (float)deg[idx[j]];
      #pragma unroll
      for (int j = 0; j < CH; ++j) xv[j] = x[(size_t)idx[j]*ldx + lane];
      #pragma unroll
      for (int j = 0; j < CH; ++j) agg += xv[j]*rsqrtf(fmaxf(dv[j], 1.f));
    }
    aggs[wv][lane] = agg * kscale;
  }
  __syncthreads();
  if (lane < DOUT){
    float o = b[lane];
    #pragma unroll 8
    for (int d = 0; d < DIN; ++d) o += aggs[wv][d] * w[d*DOUT + lane];
    out[(size_t)i*ldo + lane] = o;
  }
}

// ---------------- GAT pieces ----------------
__global__ __launch_bounds__(256) void crow_kernel(const unsigned* __restrict__ fc0max,
    const float* __restrict__ ws_, const float* __restrict__ wd_,
    float* __restrict__ c_s, float* __restrict__ c_d){
  __shared__ float hr[1024];
  int col = (blockIdx.x >> 1)*256 + threadIdx.x;
  const float* W = (blockIdx.x & 1) ? wd_ : ws_;
  float* outp = (blockIdx.x & 1) ? c_d : c_s;
  for (int j = threadIdx.x; j < 1024; j += 256) hr[j] = fdec(fc0max[j]);
  __syncthreads();
  float acc = 0.f;
  for (int d = 0; d < 1024; ++d) acc += hr[d]*W[(size_t)(192+d)*1024 + col];
  outp[col] = acc;
}

// GATv2: 512 blocks x 8 nodes; all 20 neighbor gathers in flight; single-pass softmax
__global__ __launch_bounds__(256) void gat_kernel(const int* __restrict__ nbr,
    const float* __restrict__ fs, const float* __restrict__ fd,
    const float* __restrict__ a, unsigned* __restrict__ gmax){
  int tid = threadIdx.x, lane = tid & 63, h = tid >> 6;
  float4 at = *(const float4*)&a[h*256 + lane*4];
  float runmax[4] = {-3e38f, -3e38f, -3e38f, -3e38f};
  for (int it = 0; it < 8; ++it){
    int i = blockIdx.x*8 + it;
    float4 fdv4 = *(const float4*)&fd[(size_t)i*1024 + h*256 + lane*4];
    int nb[20];
    #pragma unroll
    for (int j = 0; j < 20; ++j) nb[j] = nbr[i*20 + j];
    float4 fv[20];
    #pragma unroll
    for (int j = 0; j < 20; ++j)
      fv[j] = *(const float4*)&fs[(size_t)nb[j]*1024 + h*256 + lane*4];
    float p[20];
    #pragma unroll
    for (int j = 0; j < 20; ++j){
      float e0 = fv[j].x + fdv4.x; e0 = (e0 > 0.f) ? e0 : 0.2f*e0;
      float e1 = fv[j].y + fdv4.y; e1 = (e1 > 0.f) ? e1 : 0.2f*e1;
      float e2 = fv[j].z + fdv4.z; e2 = (e2 > 0.f) ? e2 : 0.2f*e2;
      float e3 = fv[j].w + fdv4.w; e3 = (e3 > 0.f) ? e3 : 0.2f*e3;
      p[j] = e0*at.x + e1*at.y + e2*at.z + e3*at.w;
    }
    #pragma unroll
    for (int off = 32; off; off >>= 1){
      #pragma unroll
      for (int j = 0; j < 20; ++j) p[j] += __shfl_xor(p[j], off);
    }
    float m = p[0];
    #pragma unroll
    for (int j = 1; j < 20; ++j) m = fmaxf(m, p[j]);
    float l = 0.f;
    float o[4] = {0.f, 0.f, 0.f, 0.f};
    #pragma unroll
    for (int j = 0; j < 20; ++j){
      float wj = __expf(p[j] - m);
      l += wj;
      o[0] += wj*fv[j].x; o[1] += wj*fv[j].y;
      o[2] += wj*fv[j].z; o[3] += wj*fv[j].w;
    }
    float inv = 1.f/l;
    #pragma unroll
    for (int c = 0; c < 4; ++c) runmax[c] = fmaxf(runmax[c], o[c]*inv);
  }
  #pragma unroll
  for (int c = 0; c < 4; ++c) atomicMax(&gmax[h*256 + lane*4 + c], fenc(runmax[c]));
}

__global__ __launch_bounds__(256) void head_kernel(const unsigned* __restrict__ gmax,
    const float* __restrict__ gb, const float* __restrict__ w1, const float* __restrict__ b1,
    const float* __restrict__ w2, const float* __restrict__ b2,
    const float* __restrict__ w3, const float* __restrict__ b3, float* __restrict__ out){
  __shared__ float hm[1024];
  __shared__ float s1[256];
  __shared__ float s2[64];
  int tid = threadIdx.x;
  for (int j = tid; j < 1024; j += 256) hm[j] = fdec(gmax[j]) + gb[j];
  __syncthreads();
  float acc = b1[tid];
  for (int d = 0; d < 1024; ++d) acc += hm[d]*w1[d*256+tid];
  s1[tid] = fmaxf(acc, 0.f);
  __syncthreads();
  if (tid < 64){
    float a2 = b2[tid];
    for (int d = 0; d < 256; ++d) a2 += s1[d]*w2[d*64+tid];
    s2[tid] = fmaxf(a2, 0.f);
  }
  __syncthreads();
  if (tid < 40){
    float a3 = b3[tid];
    for (int d = 0; d < 64; ++d) a3 += s2[d]*w3[d*40+tid];
    out[tid] = a3;
  }
}

// ---------------- launch ----------------
extern "C" void kernel_launch(void* const* d_in, const int* in_sizes, int n_in,
                              void* d_out, int out_size, void* d_ws, size_t ws_size,
                              hipStream_t stream){
  (void)in_sizes; (void)n_in; (void)out_size; (void)ws_size;
  const float* pc    = (const float*)d_in[0];
  const float* t_w1  = (const float*)d_in[1];
  const float* t_b1  = (const float*)d_in[2];
  const float* t_w2  = (const float*)d_in[3];
  const float* t_b2  = (const float*)d_in[4];
  const float* t_w3  = (const float*)d_in[5];
  const float* t_b3  = (const float*)d_in[6];
  const float* t_w4  = (const float*)d_in[7];
  const float* t_b4  = (const float*)d_in[8];
  const float* gc1_w = (const float*)d_in[9];
  const float* gc1_b = (const float*)d_in[10];
  const float* gc_w  = (const float*)d_in[11];
  const float* gc_b  = (const float*)d_in[12];
  const float* gp1_w = (const float*)d_in[13];
  const float* gp1_b = (const float*)d_in[14];
  const float* gp2_w = (const float*)d_in[15];
  const float* gp2_b = (const float*)d_in[16];
  const float* fc0_w = (const float*)d_in[17];
  const float* fc0_b = (const float*)d_in[18];
  const float* gat_ws= (const float*)d_in[19];
  const float* gat_wd= (const float*)d_in[20];
  const float* gat_a = (const float*)d_in[21];
  const float* gat_b = (const float*)d_in[22];
  const float* fc1_w = (const float*)d_in[23];
  const float* fc1_b = (const float*)d_in[24];
  const float* fc2_w = (const float*)d_in[25];
  const float* fc2_b = (const float*)d_in[26];
  const float* fc3_w = (const float*)d_in[27];
  const float* fc3_b = (const float*)d_in[28];
  float* out = (float*)d_out;

  char* basep = (char*)d_ws; size_t off = 0;
  auto alloc = [&](size_t bytes)->void*{
    void* p = basep + off; off += (bytes + 255) & ~(size_t)255; return p;
  };
  float* t1      = (float*)alloc((size_t)NP*64*4);
  float* x       = (float*)alloc((size_t)NP*3*4);
  float* qmat    = (float*)alloc(64);
  unsigned* tpool  = (unsigned*)alloc(1024*4);
  unsigned* fc0max = (unsigned*)alloc(1024*4);
  unsigned* gatmax = (unsigned*)alloc(1024*4);
  float* c_s     = (float*)alloc(1024*4);
  float* c_d     = (float*)alloc(1024*4);
  float4* p3     = (float4*)alloc((size_t)NP*16);
  float2* pxy    = (float2*)alloc((size_t)NP*8);
  float2* pyz    = (float2*)alloc((size_t)NP*8);
  float2* pxz    = (float2*)alloc((size_t)NP*8);
  float* tmp64   = (float*)alloc((size_t)NP*64*4);
  float* hfull   = (float*)alloc((size_t)NP*384*4);
  float* hp0     = (float*)alloc((size_t)NP*16*4);
  float* hp1     = (float*)alloc((size_t)NP*16*4);
  float* hp2     = (float*)alloc((size_t)NP*16*4);
  float* sqbuf   = (float*)alloc((size_t)NP*4);
  float* d2c     = (float*)alloc((size_t)2048*NP*4);   // 32 MB: 2048-row chunks
  int* nbr_coord = (int*)alloc((size_t)4*NP*20*4);     // [g0 | gxy | gyz | gxz]
  int* nbr_gf0   = (int*)alloc((size_t)NP*20*4);
  int* nbr_gf1   = (int*)alloc((size_t)NP*20*4);
  int* nbr_gp0   = (int*)alloc((size_t)NP*50*4);
  int* nbr_gp1   = (int*)alloc((size_t)NP*50*4);
  int* nbr_gp2   = (int*)alloc((size_t)NP*50*4);
  int* degs      = (int*)alloc((size_t)9*NP*4);
  float* fsb     = (float*)alloc((size_t)NP*1024*4);
  float* fdb     = (float*)alloc((size_t)NP*1024*4);

  int* nbr_g0  = nbr_coord + 0*NP*20;
  int* nbr_gxy = nbr_coord + 1*NP*20;
  int* nbr_gyz = nbr_coord + 2*NP*20;
  int* nbr_gxz = nbr_coord + 3*NP*20;

  const float KS20 = 0.22360679774997896f;   // 1/sqrt(20)
  const float KS50 = 0.14142135623730950f;   // 1/sqrt(50)
  const int NOMAP = 1 << 30;

  hipMemsetAsync(tpool,  0, 1024*4, stream);
  hipMemsetAsync(fc0max, 0, 1024*4, stream);
  hipMemsetAsync(gatmax, 0, 1024*4, stream);
  hipMemsetAsync(degs,   0, (size_t)9*NP*4, stream);

  // ---- T-net ----
  t1_kernel<<<NP/4, 256, 0, stream>>>(pc, t_w1, t_b1, t1);
  gemm_kernel<0,1,0,0><<<16*64, 256, 0, stream>>>(t1, 64, t_w2, 1024, t_b2,
      nullptr, tpool, 64, 64, 1024, NOMAP, 0);
  tnet_tail_kernel<<<1, 256, 0, stream>>>(tpool, t_w3, t_b3, t_w4, t_b4, qmat, out + 40);
  xform_kernel<<<16, 256, 0, stream>>>(pc, qmat, x);
  pack_kernel<<<16, 256, 0, stream>>>(x, p3, pxy, pyz, pxz);

  // ---- coordinate kNN graphs (one launch, 4 graphs) ----
  knn_coord_kernel<<<4096, 256, 0, stream>>>(p3, pxy, pyz, pxz, nbr_coord);
  deg4_kernel<<<4*NP*20/256, 256, 0, stream>>>(nbr_coord, degs);

  // ---- main branch ----
  gc_kernel<3,64,20><<<NP/4, 256, 0, stream>>>(nbr_g0, KS20, degs + 0*NP, x, 3,
      gc1_w, gc1_b, tmp64, 64);
  gc_kernel<64,64,20><<<NP/4, 256, 0, stream>>>(nbr_g0, KS20, degs + 0*NP, tmp64, 64,
      gc_w + 0*4096, gc_b + 0*64, hfull + 0, 384);
  // gf0 = knn(h0, 20)  — 2048-row chunks
  sq_kernel<<<16, 256, 0, stream>>>(hfull + 0, 384, 64, sqbuf);
  for (int ch = 0; ch < 2; ++ch){
    gemm_kernel<1,0,1,1><<<32*64, 256, 0, stream>>>(hfull + (size_t)ch*2048*384, 384,
        hfull + 0, 384, sqbuf, d2c, nullptr, 64, 64, NP, NOMAP, 0);
    topk_kernel<20><<<512, 256, 0, stream>>>(d2c, nbr_gf0 + ch*2048*20);
  }
  deg_kernel<<<(NP*20+255)/256, 256, 0, stream>>>(nbr_gf0, NP*20, degs + 4*NP);
  gc_kernel<64,64,20><<<NP/4, 256, 0, stream>>>(nbr_gf0, KS20, degs + 4*NP, hfull + 0, 384,
      gc_w + 1*4096, gc_b + 1*64, tmp64, 64);
  gc_kernel<64,64,20><<<NP/4, 256, 0, stream>>>(nbr_gf0, KS20, degs + 4*NP, tmp64, 64,
      gc_w + 2*4096, gc_b + 2*64, hfull + 64, 384);
  // gf1 = knn(h1, 20)
  sq_kernel<<<16, 256, 0, stream>>>(hfull + 64, 384, 64, sqbuf);
  for (int ch = 0; ch < 2; ++ch){
    gemm_kernel<1,0,1,1><<<32*64, 256, 0, stream>>>(hfull + 64 + (size_t)ch*2048*384, 384,
        hfull + 64, 384, sqbuf, d2c, nullptr, 64, 64, NP, NOMAP, 0);
    topk_kernel<20><<<512, 256, 0, stream>>>(d2c, nbr_gf1 + ch*2048*20);
  }
  deg_kernel<<<(NP*20+255)/256, 256, 0, stream>>>(nbr_gf1, NP*20, degs + 5*NP);
  gc_kernel<64,64,20><<<NP/4, 256, 0, stream>>>(nbr_gf1, KS20, degs + 5*NP, hfull + 64, 384,
      gc_w + 3*4096, gc_b + 3*64, hfull + 128, 384);

  // ---- plane branches ----
  int* nbr_pl[3] = {nbr_gxy, nbr_gyz, nbr_gxz};
  int* nbr_gp[3] = {nbr_gp0, nbr_gp1, nbr_gp2};
  float* hps[3]  = {hp0, hp1, hp2};
  for (int i = 0; i < 3; ++i){
    gc_kernel<3,16,20><<<NP/4, 256, 0, stream>>>(nbr_pl[i], KS20, degs + (1+i)*NP, x, 3,
        gp1_w + i*48, gp1_b + i*16, hps[i], 16);
    sq_kernel<<<16, 256, 0, stream>>>(hps[i], 16, 16, sqbuf);
    for (int ch = 0; ch < 2; ++ch){
      gemm_kernel<1,0,1,1><<<32*64, 256, 0, stream>>>(hps[i] + (size_t)ch*2048*16, 16,
          hps[i], 16, sqbuf, d2c, nullptr, 32, 16, NP, NOMAP, 0);
      topk_kernel<50><<<512, 256, 0, stream>>>(d2c, nbr_gp[i] + ch*2048*50);
    }
    deg_kernel<<<(NP*50+255)/256, 256, 0, stream>>>(nbr_gp[i], NP*50, degs + (6+i)*NP);
    gc_kernel<16,64,50><<<NP/4, 256, 0, stream>>>(nbr_gp[i], KS50, degs + (6+i)*NP,
        hps[i], 16, gp2_w + i*1024, gp2_b + i*64, hfull + 192 + 64*i, 384);
  }

  // ---- fc0 + max, then fs/fd GEMMs with h_ folded in as a per-column constant ----
  gemm_kernel<0,1,0,0><<<16*64, 256, 0, stream>>>(hfull, 384, fc0_w, 1024, fc0_b,
      nullptr, fc0max, 192, 192, 1024, NOMAP, 0);
  crow_kernel<<<8, 256, 0, stream>>>(fc0max, gat_ws, gat_wd, c_s, c_d);
  gemm_kernel<1,0,0,0><<<16*64, 256, 0, stream>>>(hfull, 384, gat_ws, 1024, c_s,
      fsb, nullptr, 384, 384, 1024, 192, 1024);
  gemm_kernel<1,0,0,0><<<16*64, 256, 0, stream>>>(hfull, 384, gat_wd, 1024, c_d,
      fdb, nullptr, 384, 384, 1024, 192, 1024);

  // ---- GATv2 + head ----
  gat_kernel<<<NP/8, 256, 0, stream>>>(nbr_g0, fsb, fdb, gat_a, gatmax);
  head_kernel<<<1, 256, 0, stream>>>(gatmax, gat_b, fc1_w, fc1_b, fc2_w, fc2_b,
      fc3_w, fc3_b, out);
}

// Round 10
// 1356.428 us; speedup vs baseline: 1.7142x; 1.0567x over previous
//
#include <hip/hip_runtime.h>
#include <math.h>

#define NP 4096

// ---------------- helpers ----------------
__device__ inline unsigned fenc(float f){
  unsigned b = __float_as_uint(f);
  return (b & 0x80000000u) ? ~b : (b | 0x80000000u);
}
__device__ inline float fdec(unsigned u){
  return (u & 0x80000000u) ? __uint_as_float(u ^ 0x80000000u) : __uint_as_float(~u);
}

// ---------------- T-net ----------------
__global__ __launch_bounds__(256) void t1_kernel(const float* __restrict__ pc,
    const float* __restrict__ w1, const float* __restrict__ b1, float* __restrict__ t1){
  int i = blockIdx.x*4 + (threadIdx.x>>6);
  int o = threadIdx.x & 63;
  float p0 = pc[i*3+0], p1 = pc[i*3+1], p2 = pc[i*3+2];
  float v = p0*w1[o] + p1*w1[64+o] + p2*w1[128+o] + b1[o];
  t1[i*64+o] = fmaxf(v, 0.f);
}

__global__ __launch_bounds__(256) void tnet_tail_kernel(const unsigned* __restrict__ tpool,
    const float* __restrict__ w3, const float* __restrict__ b3,
    const float* __restrict__ w4, const float* __restrict__ b4,
    float* __restrict__ qmat, float* __restrict__ rout){
  __shared__ float tp[1024];
  __shared__ float t3[256];
  __shared__ float t4[9];
  int tid = threadIdx.x;
  for (int j = tid; j < 1024; j += 256) tp[j] = fdec(tpool[j]);
  __syncthreads();
  float acc = b3[tid];
  for (int d = 0; d < 1024; ++d) acc += tp[d]*w3[d*256+tid];
  t3[tid] = fmaxf(acc, 0.f);
  __syncthreads();
  if (tid < 9){
    float a = b4[tid];
    for (int d = 0; d < 256; ++d) a += t3[d]*w4[d*9+tid];
    t4[tid] = a;
  }
  __syncthreads();
  if (tid == 0){
    float a00=t4[0], a01=t4[1], a02=t4[2];
    float a10=t4[3], a11=t4[4], a12=t4[5];
    float a20=t4[6], a21=t4[7], a22=t4[8];
    // Householder QR, LAPACK sign convention (beta = -sign(alpha)*norm)
    float tau0 = 0.f, v1 = 0.f, v2 = 0.f;
    float xn2 = a10*a10 + a20*a20;
    if (xn2 > 0.f){
      float alpha = a00;
      float nrm = sqrtf(alpha*alpha + xn2);
      float beta = (alpha >= 0.f) ? -nrm : nrm;
      tau0 = (beta - alpha)/beta;
      float inv = 1.f/(alpha - beta);
      v1 = a10*inv; v2 = a20*inv;
      float s1 = a01 + v1*a11 + v2*a21; s1 *= tau0;
      a01 -= s1; a11 -= v1*s1; a21 -= v2*s1;
      float s2 = a02 + v1*a12 + v2*a22; s2 *= tau0;
      a02 -= s2; a12 -= v1*s2; a22 -= v2*s2;
      a00 = beta;
    }
    float tau1 = 0.f, wv = 0.f;
    float xn1 = a21*a21;
    if (xn1 > 0.f){
      float alpha = a11;
      float nrm = sqrtf(alpha*alpha + xn1);
      float beta = (alpha >= 0.f) ? -nrm : nrm;
      tau1 = (beta - alpha)/beta;
      wv = a21/(alpha - beta);
      float s = a12 + wv*a22; s *= tau1;
      a12 -= s; a22 -= wv*s;
      a11 = beta;
    }
    rout[0]=a00; rout[1]=a01; rout[2]=a02;
    rout[3]=0.f; rout[4]=a11; rout[5]=a12;
    rout[6]=0.f; rout[7]=0.f; rout[8]=a22;
    // Q = H0 * H1
    float M[3][3] = {{1,0,0},{0,1,0},{0,0,1}};
    M[1][1] -= tau1;     M[1][2] -= tau1*wv;
    M[2][1] -= tau1*wv;  M[2][2] -= tau1*wv*wv;
    #pragma unroll
    for (int c = 0; c < 3; ++c){
      float p = M[0][c] + v1*M[1][c] + v2*M[2][c];
      qmat[0*3+c] = M[0][c] - tau0*p;
      qmat[1*3+c] = M[1][c] - tau0*v1*p;
      qmat[2*3+c] = M[2][c] - tau0*v2*p;
    }
  }
}

__global__ __launch_bounds__(256) void xform_kernel(const float* __restrict__ pc,
    const float* __restrict__ q, float* __restrict__ x){
  int i = blockIdx.x*256 + threadIdx.x;
  if (i >= NP) return;
  float p0 = pc[i*3+0], p1 = pc[i*3+1], p2 = pc[i*3+2];
  x[i*3+0] = p0*q[0] + p1*q[3] + p2*q[6];
  x[i*3+1] = p0*q[1] + p1*q[4] + p2*q[7];
  x[i*3+2] = p0*q[2] + p1*q[5] + p2*q[8];
}

// pack transformed coords into coalescing-friendly layouts (L2-resident)
__global__ __launch_bounds__(256) void pack_kernel(const float* __restrict__ x,
    float4* __restrict__ p3, float2* __restrict__ pxy,
    float2* __restrict__ pyz, float2* __restrict__ pxz){
  int i = blockIdx.x*256 + threadIdx.x;
  if (i >= NP) return;
  float a = x[i*3], b = x[i*3+1], c = x[i*3+2];
  p3[i]  = make_float4(a, b, c, 0.f);
  pxy[i] = make_float2(a, b);
  pyz[i] = make_float2(b, c);
  pxz[i] = make_float2(a, c);
}

// ---------------- generic f32 GEMM (M x K @ K x ncols), 64x64 tiles ----------------
template<int STORE, int COLMAX, int BT, int D2EPI>
__global__ __launch_bounds__(256) void gemm_kernel(
    const float* __restrict__ A, int lda,
    const float* __restrict__ B, int ldb,
    const float* __restrict__ bias,
    float* __restrict__ C, unsigned* __restrict__ cmax,
    int kloop, int kreal, int ncols, int remap_thresh, int remap_shift){
  __shared__ float As[32][68];
  __shared__ float Bs[32][68];
  int tid = threadIdx.x;
  int nbx = ncols >> 6;
  int bx = blockIdx.x % nbx, by = blockIdx.x / nbx;
  int tx = tid & 15, ty = tid >> 4;
  int row0 = by*64, col0 = bx*64;
  float acc[4][4];
  #pragma unroll
  for (int r = 0; r < 4; ++r)
    #pragma unroll
    for (int c = 0; c < 4; ++c) acc[r][c] = 0.f;

  for (int kt = 0; kt < kloop; kt += 32){
    {
      int m = tid & 63, kq = tid >> 6;
      #pragma unroll
      for (int h = 0; h < 2; ++h){
        int k4 = kq + h*4;
        float4 av = make_float4(0.f,0.f,0.f,0.f);
        if (kt + k4*4 < kreal)
          av = *(const float4*)&A[(size_t)(row0+m)*lda + kt + k4*4];
        As[k4*4+0][m] = av.x; As[k4*4+1][m] = av.y;
        As[k4*4+2][m] = av.z; As[k4*4+3][m] = av.w;
      }
    }
    if (BT){
      int c = tid & 63, kq = tid >> 6;
      #pragma unroll
      for (int h = 0; h < 2; ++h){
        int k4 = kq + h*4;
        float4 bv = make_float4(0.f,0.f,0.f,0.f);
        if (kt + k4*4 < kreal)
          bv = *(const float4*)&B[(size_t)(col0+c)*ldb + kt + k4*4];
        Bs[k4*4+0][c] = bv.x; Bs[k4*4+1][c] = bv.y;
        Bs[k4*4+2][c] = bv.z; Bs[k4*4+3][c] = bv.w;
      }
    } else {
      int k = tid & 31, cq = tid >> 5;
      #pragma unroll
      for (int h = 0; h < 2; ++h){
        int c4 = cq + h*8;
        int krow = kt + k;
        int brow = (krow >= remap_thresh) ? krow + remap_shift : krow;
        float4 bv = *(const float4*)&B[(size_t)brow*ldb + col0 + c4*4];
        *(float4*)&Bs[k][c4*4] = bv;
      }
    }
    __syncthreads();
    #pragma unroll
    for (int k = 0; k < 32; ++k){
      float4 a4 = *(const float4*)&As[k][ty*4];
      float4 b4 = *(const float4*)&Bs[k][tx*4];
      float av[4] = {a4.x, a4.y, a4.z, a4.w};
      float bv[4] = {b4.x, b4.y, b4.z, b4.w};
      #pragma unroll
      for (int r = 0; r < 4; ++r)
        #pragma unroll
        for (int c = 0; c < 4; ++c) acc[r][c] += av[r]*bv[c];
    }
    __syncthreads();
  }
  float bvv[4];
  #pragma unroll
  for (int c = 0; c < 4; ++c) bvv[c] = bias[col0 + tx*4 + c];
  float val[4][4];
  #pragma unroll
  for (int r = 0; r < 4; ++r)
    #pragma unroll
    for (int c = 0; c < 4; ++c)
      val[r][c] = D2EPI ? (bvv[c] - 2.f*acc[r][c]) : (acc[r][c] + bvv[c]);
  if (STORE){
    #pragma unroll
    for (int r = 0; r < 4; ++r){
      float4 v = make_float4(val[r][0], val[r][1], val[r][2], val[r][3]);
      *(float4*)&C[(size_t)(row0 + ty*4 + r)*ncols + col0 + tx*4] = v;
    }
  }
  if (COLMAX){
    float cm[4];
    #pragma unroll
    for (int c = 0; c < 4; ++c)
      cm[c] = fmaxf(fmaxf(val[0][c], val[1][c]), fmaxf(val[2][c], val[3][c]));
    float* red = (float*)As;
    #pragma unroll
    for (int c = 0; c < 4; ++c) red[ty*64 + tx*4 + c] = cm[c];
    __syncthreads();
    if (tid < 64){
      float m = red[tid];
      #pragma unroll
      for (int t = 1; t < 16; ++t) m = fmaxf(m, red[t*64 + tid]);
      atomicMax(&cmax[col0 + tid], fenc(m));
    }
  }
}

// ---------------- top-k extraction, register-resident ----------------
// lane L owns slots j with (j&63)==L, held in v[8][8] registers (all indices
// compile-time). Per round: wave argmin (2-chain butterfly), then the winning
// group gw = ii>>9 is WAVE-UNIFORM -> uniform branch re-scans only that group
// in registers (8 cndmask + 8-min tree). No LDS at all.
template<int K>
__device__ inline void extract_topk_reg(float (&v)[8][8], int lane,
    int* __restrict__ nbr_row){
  float gmin[8]; int gidx[8];
  #pragma unroll
  for (int g = 0; g < 8; ++g){
    float mv = v[g][0]; int mi = g*512 + lane;
    #pragma unroll
    for (int e = 1; e < 8; ++e){
      int j = (g*8 + e)*64 + lane;
      bool c = v[g][e] < mv;           // strict < keeps lowest j on ties
      mv = c ? v[g][e] : mv; mi = c ? j : mi;
    }
    gmin[g] = mv; gidx[g] = mi;
  }
  float lv = gmin[0]; int li = gidx[0];
  #pragma unroll
  for (int g = 1; g < 8; ++g){
    bool c = (gmin[g] < lv) || (gmin[g] == lv && gidx[g] < li);
    lv = c ? gmin[g] : lv; li = c ? gidx[g] : li;
  }
  int keep = 0;
  for (int r = 0; r < K; ++r){
    float vv = lv; int ii = li;
    #pragma unroll
    for (int off = 32; off; off >>= 1){
      float ov = __shfl_xor(vv, off);
      int oi = __shfl_xor(ii, off);
      bool c = (ov < vv) || (ov == vv && oi < ii);
      vv = c ? ov : vv; ii = c ? oi : ii;
    }
    if (lane == r) keep = ii;
    int gw = ii >> 9;                  // wave-uniform
    int ew = (ii >> 6) & 7;            // wave-uniform
    bool own = (ii & 63) == lane;
    #pragma unroll
    for (int g = 0; g < 8; ++g){
      if (g == gw){                    // uniform branch; one group taken
        #pragma unroll
        for (int e = 0; e < 8; ++e){
          bool kill = own && (ew == e);
          v[g][e] = kill ? 3e38f : v[g][e];
        }
        float mv = v[g][0]; int mi = g*512 + lane;
        #pragma unroll
        for (int e = 1; e < 8; ++e){
          int j = (g*8 + e)*64 + lane;
          bool c = v[g][e] < mv;
          mv = c ? v[g][e] : mv; mi = c ? j : mi;
        }
        gmin[g] = mv; gidx[g] = mi;
      }
    }
    lv = gmin[0]; li = gidx[0];
    #pragma unroll
    for (int g = 1; g < 8; ++g){
      bool c = (gmin[g] < lv) || (gmin[g] == lv && gidx[g] < li);
      lv = c ? gmin[g] : lv; li = c ? gidx[g] : li;
    }
  }
  if (lane < K) nbr_row[lane] = keep;
}

// all 4 coordinate kNN graphs in one launch; zero LDS, d2 straight to registers
__global__ __launch_bounds__(256) void knn_coord_kernel(const float4* __restrict__ p3,
    const float2* __restrict__ pxy, const float2* __restrict__ pyz,
    const float2* __restrict__ pxz, int* __restrict__ nbr4){
  int tid = threadIdx.x, lane = tid & 63, w = tid >> 6;
  int gsel = blockIdx.x >> 10;
  int i = (blockIdx.x & 1023)*4 + w;
  float v[8][8];
  if (gsel == 0){
    float4 q = p3[i];
    #pragma unroll
    for (int g = 0; g < 8; ++g)
      #pragma unroll
      for (int e = 0; e < 8; ++e){
        int j = (g*8 + e)*64 + lane;
        float4 p = p3[j];
        v[g][e] = (p.x*p.x + p.y*p.y + p.z*p.z) - 2.f*(p.x*q.x + p.y*q.y + p.z*q.z);
      }
  } else {
    const float2* pp = (gsel == 1) ? pxy : (gsel == 2) ? pyz : pxz;
    float2 q = pp[i];
    #pragma unroll
    for (int g = 0; g < 8; ++g)
      #pragma unroll
      for (int e = 0; e < 8; ++e){
        int j = (g*8 + e)*64 + lane;
        float2 p = pp[j];
        v[g][e] = (p.x*p.x + p.y*p.y) - 2.f*(p.x*q.x + p.y*q.y);
      }
  }
  extract_topk_reg<20>(v, lane, &nbr4[(size_t)gsel*NP*20 + i*20]);
}

// top-k from a precomputed (chunked) d2 matrix; zero LDS
template<int K>
__global__ __launch_bounds__(256) void topk_kernel(const float* __restrict__ d2m,
    int* __restrict__ nbr_chunk){
  int tid = threadIdx.x, lane = tid & 63, w = tid >> 6;
  int il = blockIdx.x*4 + w;
  float v[8][8];
  #pragma unroll
  for (int g = 0; g < 8; ++g)
    #pragma unroll
    for (int e = 0; e < 8; ++e)
      v[g][e] = d2m[(size_t)il*NP + (g*8 + e)*64 + lane];
  extract_topk_reg<K>(v, lane, &nbr_chunk[il*K]);
}

// ---------------- graph utilities ----------------
__global__ __launch_bounds__(256) void sq_kernel(const float* __restrict__ f, int ld, int D,
    float* __restrict__ sq){
  int i = blockIdx.x*256 + threadIdx.x;
  if (i >= NP) return;
  float s = 0.f;
  for (int c = 0; c < D; c += 4){
    float4 v = *(const float4*)&f[(size_t)i*ld + c];
    s += v.x*v.x + v.y*v.y + v.z*v.z + v.w*v.w;
  }
  sq[i] = s;
}

__global__ __launch_bounds__(256) void deg_kernel(const int* __restrict__ nbr, int total,
    int* __restrict__ deg){
  int e = blockIdx.x*256 + threadIdx.x;
  if (e < total) atomicAdd(&deg[nbr[e]], 1);
}

// degree counting for the 4 coordinate graphs in one launch
__global__ __launch_bounds__(256) void deg4_kernel(const int* __restrict__ nbr4,
    int* __restrict__ degs){
  int e = blockIdx.x*256 + threadIdx.x;
  int g = e / (NP*20);
  atomicAdd(&degs[g*NP + nbr4[e]], 1);
}

// DGL GraphConv norm='both', neighbor count templated; gathers batched 10-deep
template<int DIN, int DOUT, int KNB>
__global__ __launch_bounds__(256) void gc_kernel(const int* __restrict__ nbr, float kscale,
    const int* __restrict__ deg, const float* __restrict__ x, int ldx,
    const float* __restrict__ w, const float* __restrict__ b,
    float* __restrict__ out, int ldo){
  __shared__ float aggs[4][DIN];
  int tid = threadIdx.x, lane = tid & 63, wv = tid >> 6;
  int i = blockIdx.x*4 + wv;
  if (lane < DIN){
    float agg = 0.f;
    constexpr int CH = (KNB % 10 == 0) ? 10 : KNB;
    #pragma unroll
    for (int jj = 0; jj < KNB; jj += CH){
      int idx[CH]; float dv[CH]; float xv[CH];
      #pragma unroll
      for (int j = 0; j < CH; ++j) idx[j] = nbr[i*KNB + jj + j];
      #pragma unroll
      for (int j = 0; j < CH; ++j) dv[j] = (float)deg[idx[j]];
      #pragma unroll
      for (int j = 0; j < CH; ++j) xv[j] = x[(size_t)idx[j]*ldx + lane];
      #pragma unroll
      for (int j = 0; j < CH; ++j) agg += xv[j]*rsqrtf(fmaxf(dv[j], 1.f));
    }
    aggs[wv][lane] = agg * kscale;
  }
  __syncthreads();
  if (lane < DOUT){
    float o = b[lane];
    #pragma unroll 8
    for (int d = 0; d < DIN; ++d) o += aggs[wv][d] * w[d*DOUT + lane];
    out[(size_t)i*ldo + lane] = o;
  }
}

// ---------------- GAT pieces ----------------
__global__ __launch_bounds__(256) void crow_kernel(const unsigned* __restrict__ fc0max,
    const float* __restrict__ ws_, const float* __restrict__ wd_,
    float* __restrict__ c_s, float* __restrict__ c_d){
  __shared__ float hr[1024];
  int col = (blockIdx.x >> 1)*256 + threadIdx.x;
  const float* W = (blockIdx.x & 1) ? wd_ : ws_;
  float* outp = (blockIdx.x & 1) ? c_d : c_s;
  for (int j = threadIdx.x; j < 1024; j += 256) hr[j] = fdec(fc0max[j]);
  __syncthreads();
  float acc = 0.f;
  for (int d = 0; d < 1024; ++d) acc += hr[d]*W[(size_t)(192+d)*1024 + col];
  outp[col] = acc;
}

// GATv2: 512 blocks x 8 nodes; all 20 neighbor gathers in flight; single-pass softmax
__global__ __launch_bounds__(256) void gat_kernel(const int* __restrict__ nbr,
    const float* __restrict__ fs, const float* __restrict__ fd,
    const float* __restrict__ a, unsigned* __restrict__ gmax){
  int tid = threadIdx.x, lane = tid & 63, h = tid >> 6;
  float4 at = *(const float4*)&a[h*256 + lane*4];
  float runmax[4] = {-3e38f, -3e38f, -3e38f, -3e38f};
  for (int it = 0; it < 8; ++it){
    int i = blockIdx.x*8 + it;
    float4 fdv4 = *(const float4*)&fd[(size_t)i*1024 + h*256 + lane*4];
    int nb[20];
    #pragma unroll
    for (int j = 0; j < 20; ++j) nb[j] = nbr[i*20 + j];
    float4 fv[20];
    #pragma unroll
    for (int j = 0; j < 20; ++j)
      fv[j] = *(const float4*)&fs[(size_t)nb[j]*1024 + h*256 + lane*4];
    float p[20];
    #pragma unroll
    for (int j = 0; j < 20; ++j){
      float e0 = fv[j].x + fdv4.x; e0 = (e0 > 0.f) ? e0 : 0.2f*e0;
      float e1 = fv[j].y + fdv4.y; e1 = (e1 > 0.f) ? e1 : 0.2f*e1;
      float e2 = fv[j].z + fdv4.z; e2 = (e2 > 0.f) ? e2 : 0.2f*e2;
      float e3 = fv[j].w + fdv4.w; e3 = (e3 > 0.f) ? e3 : 0.2f*e3;
      p[j] = e0*at.x + e1*at.y + e2*at.z + e3*at.w;
    }
    #pragma unroll
    for (int off = 32; off; off >>= 1){
      #pragma unroll
      for (int j = 0; j < 20; ++j) p[j] += __shfl_xor(p[j], off);
    }
    float m = p[0];
    #pragma unroll
    for (int j = 1; j < 20; ++j) m = fmaxf(m, p[j]);
    float l = 0.f;
    float o[4] = {0.f, 0.f, 0.f, 0.f};
    #pragma unroll
    for (int j = 0; j < 20; ++j){
      float wj = __expf(p[j] - m);
      l += wj;
      o[0] += wj*fv[j].x; o[1] += wj*fv[j].y;
      o[2] += wj*fv[j].z; o[3] += wj*fv[j].w;
    }
    float inv = 1.f/l;
    #pragma unroll
    for (int c = 0; c < 4; ++c) runmax[c] = fmaxf(runmax[c], o[c]*inv);
  }
  #pragma unroll
  for (int c = 0; c < 4; ++c) atomicMax(&gmax[h*256 + lane*4 + c], fenc(runmax[c]));
}

__global__ __launch_bounds__(256) void head_kernel(const unsigned* __restrict__ gmax,
    const float* __restrict__ gb, const float* __restrict__ w1, const float* __restrict__ b1,
    const float* __restrict__ w2, const float* __restrict__ b2,
    const float* __restrict__ w3, const float* __restrict__ b3, float* __restrict__ out){
  __shared__ float hm[1024];
  __shared__ float s1[256];
  __shared__ float s2[64];
  int tid = threadIdx.x;
  for (int j = tid; j < 1024; j += 256) hm[j] = fdec(gmax[j]) + gb[j];
  __syncthreads();
  float acc = b1[tid];
  for (int d = 0; d < 1024; ++d) acc += hm[d]*w1[d*256+tid];
  s1[tid] = fmaxf(acc, 0.f);
  __syncthreads();
  if (tid < 64){
    float a2 = b2[tid];
    for (int d = 0; d < 256; ++d) a2 += s1[d]*w2[d*64+tid];
    s2[tid] = fmaxf(a2, 0.f);
  }
  __syncthreads();
  if (tid < 40){
    float a3 = b3[tid];
    for (int d = 0; d < 64; ++d) a3 += s2[d]*w3[d*40+tid];
    out[tid] = a3;
  }
}

// ---------------- launch ----------------
extern "C" void kernel_launch(void* const* d_in, const int* in_sizes, int n_in,
                              void* d_out, int out_size, void* d_ws, size_t ws_size,
                              hipStream_t stream){
  (void)in_sizes; (void)n_in; (void)out_size; (void)ws_size;
  const float* pc    = (const float*)d_in[0];
  const float* t_w1  = (const float*)d_in[1];
  const float* t_b1  = (const float*)d_in[2];
  const float* t_w2  = (const float*)d_in[3];
  const float* t_b2  = (const float*)d_in[4];
  const float* t_w3  = (const float*)d_in[5];
  const float* t_b3  = (const float*)d_in[6];
  const float* t_w4  = (const float*)d_in[7];
  const float* t_b4  = (const float*)d_in[8];
  const float* gc1_w = (const float*)d_in[9];
  const float* gc1_b = (const float*)d_in[10];
  const float* gc_w  = (const float*)d_in[11];
  const float* gc_b  = (const float*)d_in[12];
  const float* gp1_w = (const float*)d_in[13];
  const float* gp1_b = (const float*)d_in[14];
  const float* gp2_w = (const float*)d_in[15];
  const float* gp2_b = (const float*)d_in[16];
  const float* fc0_w = (const float*)d_in[17];
  const float* fc0_b = (const float*)d_in[18];
  const float* gat_ws= (const float*)d_in[19];
  const float* gat_wd= (const float*)d_in[20];
  const float* gat_a = (const float*)d_in[21];
  const float* gat_b = (const float*)d_in[22];
  const float* fc1_w = (const float*)d_in[23];
  const float* fc1_b = (const float*)d_in[24];
  const float* fc2_w = (const float*)d_in[25];
  const float* fc2_b = (const float*)d_in[26];
  const float* fc3_w = (const float*)d_in[27];
  const float* fc3_b = (const float*)d_in[28];
  float* out = (float*)d_out;

  char* basep = (char*)d_ws; size_t off = 0;
  auto alloc = [&](size_t bytes)->void*{
    void* p = basep + off; off += (bytes + 255) & ~(size_t)255; return p;
  };
  float* t1      = (float*)alloc((size_t)NP*64*4);
  float* x       = (float*)alloc((size_t)NP*3*4);
  float* qmat    = (float*)alloc(64);
  unsigned* tpool  = (unsigned*)alloc(1024*4);
  unsigned* fc0max = (unsigned*)alloc(1024*4);
  unsigned* gatmax = (unsigned*)alloc(1024*4);
  float* c_s     = (float*)alloc(1024*4);
  float* c_d     = (float*)alloc(1024*4);
  float4* p3     = (float4*)alloc((size_t)NP*16);
  float2* pxy    = (float2*)alloc((size_t)NP*8);
  float2* pyz    = (float2*)alloc((size_t)NP*8);
  float2* pxz    = (float2*)alloc((size_t)NP*8);
  float* tmp64   = (float*)alloc((size_t)NP*64*4);
  float* hfull   = (float*)alloc((size_t)NP*384*4);
  float* hp0     = (float*)alloc((size_t)NP*16*4);
  float* hp1     = (float*)alloc((size_t)NP*16*4);
  float* hp2     = (float*)alloc((size_t)NP*16*4);
  float* sqbuf   = (float*)alloc((size_t)NP*4);
  float* d2c     = (float*)alloc((size_t)2048*NP*4);   // 32 MB: 2048-row chunks
  int* nbr_coord = (int*)alloc((size_t)4*NP*20*4);     // [g0 | gxy | gyz | gxz]
  int* nbr_gf0   = (int*)alloc((size_t)NP*20*4);
  int* nbr_gf1   = (int*)alloc((size_t)NP*20*4);
  int* nbr_gp0   = (int*)alloc((size_t)NP*50*4);
  int* nbr_gp1   = (int*)alloc((size_t)NP*50*4);
  int* nbr_gp2   = (int*)alloc((size_t)NP*50*4);
  int* degs      = (int*)alloc((size_t)9*NP*4);
  float* fsb     = (float*)alloc((size_t)NP*1024*4);
  float* fdb     = (float*)alloc((size_t)NP*1024*4);

  int* nbr_g0  = nbr_coord + 0*NP*20;
  int* nbr_gxy = nbr_coord + 1*NP*20;
  int* nbr_gyz = nbr_coord + 2*NP*20;
  int* nbr_gxz = nbr_coord + 3*NP*20;

  const float KS20 = 0.22360679774997896f;   // 1/sqrt(20)
  const float KS50 = 0.14142135623730950f;   // 1/sqrt(50)
  const int NOMAP = 1 << 30;

  hipMemsetAsync(tpool,  0, 1024*4, stream);
  hipMemsetAsync(fc0max, 0, 1024*4, stream);
  hipMemsetAsync(gatmax, 0, 1024*4, stream);
  hipMemsetAsync(degs,   0, (size_t)9*NP*4, stream);

  // ---- T-net ----
  t1_kernel<<<NP/4, 256, 0, stream>>>(pc, t_w1, t_b1, t1);
  gemm_kernel<0,1,0,0><<<16*64, 256, 0, stream>>>(t1, 64, t_w2, 1024, t_b2,
      nullptr, tpool, 64, 64, 1024, NOMAP, 0);
  tnet_tail_kernel<<<1, 256, 0, stream>>>(tpool, t_w3, t_b3, t_w4, t_b4, qmat, out + 40);
  xform_kernel<<<16, 256, 0, stream>>>(pc, qmat, x);
  pack_kernel<<<16, 256, 0, stream>>>(x, p3, pxy, pyz, pxz);

  // ---- coordinate kNN graphs (one launch, 4 graphs) ----
  knn_coord_kernel<<<4096, 256, 0, stream>>>(p3, pxy, pyz, pxz, nbr_coord);
  deg4_kernel<<<4*NP*20/256, 256, 0, stream>>>(nbr_coord, degs);

  // ---- main branch ----
  gc_kernel<3,64,20><<<NP/4, 256, 0, stream>>>(nbr_g0, KS20, degs + 0*NP, x, 3,
      gc1_w, gc1_b, tmp64, 64);
  gc_kernel<64,64,20><<<NP/4, 256, 0, stream>>>(nbr_g0, KS20, degs + 0*NP, tmp64, 64,
      gc_w + 0*4096, gc_b + 0*64, hfull + 0, 384);
  // gf0 = knn(h0, 20)  — 2048-row chunks
  sq_kernel<<<16, 256, 0, stream>>>(hfull + 0, 384, 64, sqbuf);
  for (int ch = 0; ch < 2; ++ch){
    gemm_kernel<1,0,1,1><<<32*64, 256, 0, stream>>>(hfull + (size_t)ch*2048*384, 384,
        hfull + 0, 384, sqbuf, d2c, nullptr, 64, 64, NP, NOMAP, 0);
    topk_kernel<20><<<512, 256, 0, stream>>>(d2c, nbr_gf0 + ch*2048*20);
  }
  deg_kernel<<<(NP*20+255)/256, 256, 0, stream>>>(nbr_gf0, NP*20, degs + 4*NP);
  gc_kernel<64,64,20><<<NP/4, 256, 0, stream>>>(nbr_gf0, KS20, degs + 4*NP, hfull + 0, 384,
      gc_w + 1*4096, gc_b + 1*64, tmp64, 64);
  gc_kernel<64,64,20><<<NP/4, 256, 0, stream>>>(nbr_gf0, KS20, degs + 4*NP, tmp64, 64,
      gc_w + 2*4096, gc_b + 2*64, hfull + 64, 384);
  // gf1 = knn(h1, 20)
  sq_kernel<<<16, 256, 0, stream>>>(hfull + 64, 384, 64, sqbuf);
  for (int ch = 0; ch < 2; ++ch){
    gemm_kernel<1,0,1,1><<<32*64, 256, 0, stream>>>(hfull + 64 + (size_t)ch*2048*384, 384,
        hfull + 64, 384, sqbuf, d2c, nullptr, 64, 64, NP, NOMAP, 0);
    topk_kernel<20><<<512, 256, 0, stream>>>(d2c, nbr_gf1 + ch*2048*20);
  }
  deg_kernel<<<(NP*20+255)/256, 256, 0, stream>>>(nbr_gf1, NP*20, degs + 5*NP);
  gc_kernel<64,64,20><<<NP/4, 256, 0, stream>>>(nbr_gf1, KS20, degs + 5*NP, hfull + 64, 384,
      gc_w + 3*4096, gc_b + 3*64, hfull + 128, 384);

  // ---- plane branches ----
  int* nbr_pl[3] = {nbr_gxy, nbr_gyz, nbr_gxz};
  int* nbr_gp[3] = {nbr_gp0, nbr_gp1, nbr_gp2};
  float* hps[3]  = {hp0, hp1, hp2};
  for (int i = 0; i < 3; ++i){
    gc_kernel<3,16,20><<<NP/4, 256, 0, stream>>>(nbr_pl[i], KS20, degs + (1+i)*NP, x, 3,
        gp1_w + i*48, gp1_b + i*16, hps[i], 16);
    sq_kernel<<<16, 256, 0, stream>>>(hps[i], 16, 16, sqbuf);
    for (int ch = 0; ch < 2; ++ch){
      gemm_kernel<1,0,1,1><<<32*64, 256, 0, stream>>>(hps[i] + (size_t)ch*2048*16, 16,
          hps[i], 16, sqbuf, d2c, nullptr, 32, 16, NP, NOMAP, 0);
      topk_kernel<50><<<512, 256, 0, stream>>>(d2c, nbr_gp[i] + ch*2048*50);
    }
    deg_kernel<<<(NP*50+255)/256, 256, 0, stream>>>(nbr_gp[i], NP*50, degs + (6+i)*NP);
    gc_kernel<16,64,50><<<NP/4, 256, 0, stream>>>(nbr_gp[i], KS50, degs + (6+i)*NP,
        hps[i], 16, gp2_w + i*1024, gp2_b + i*64, hfull + 192 + 64*i, 384);
  }

  // ---- fc0 + max, then fs/fd GEMMs with h_ folded in as a per-column constant ----
  gemm_kernel<0,1,0,0><<<16*64, 256, 0, stream>>>(hfull, 384, fc0_w, 1024, fc0_b,
      nullptr, fc0max, 192, 192, 1024, NOMAP, 0);
  crow_kernel<<<8, 256, 0, stream>>>(fc0max, gat_ws, gat_wd, c_s, c_d);
  gemm_kernel<1,0,0,0><<<16*64, 256, 0, stream>>>(hfull, 384, gat_ws, 1024, c_s,
      fsb, nullptr, 384, 384, 1024, 192, 1024);
  gemm_kernel<1,0,0,0><<<16*64, 256, 0, stream>>>(hfull, 384, gat_wd, 1024, c_d,
      fdb, nullptr, 384, 384, 1024, 192, 1024);

  // ---- GATv2 + head ----
  gat_kernel<<<NP/8, 256, 0, stream>>>(nbr_g0, fsb, fdb, gat_a, gatmax);
  head_kernel<<<1, 256, 0, stream>>>(gatmax, gat_b, fc1_w, fc1_b, fc2_w, fc2_b,
      fc3_w, fc3_b, out);
}

// Round 11
// 1346.076 us; speedup vs baseline: 1.7274x; 1.0077x over previous
//
#include <hip/hip_runtime.h>
#include <math.h>

#define NP 4096

// ---------------- helpers ----------------
__device__ inline unsigned fenc(float f){
  unsigned b = __float_as_uint(f);
  return (b & 0x80000000u) ? ~b : (b | 0x80000000u);
}
__device__ inline float fdec(unsigned u){
  return (u & 0x80000000u) ? __uint_as_float(u ^ 0x80000000u) : __uint_as_float(~u);
}

// ---------------- T-net ----------------
__global__ __launch_bounds__(256) void t1_kernel(const float* __restrict__ pc,
    const float* __restrict__ w1, const float* __restrict__ b1, float* __restrict__ t1){
  int i = blockIdx.x*4 + (threadIdx.x>>6);
  int o = threadIdx.x & 63;
  float p0 = pc[i*3+0], p1 = pc[i*3+1], p2 = pc[i*3+2];
  float v = p0*w1[o] + p1*w1[64+o] + p2*w1[128+o] + b1[o];
  t1[i*64+o] = fmaxf(v, 0.f);
}

__global__ __launch_bounds__(256) void tnet_tail_kernel(const unsigned* __restrict__ tpool,
    const float* __restrict__ w3, const float* __restrict__ b3,
    const float* __restrict__ w4, const float* __restrict__ b4,
    float* __restrict__ qmat, float* __restrict__ rout){
  __shared__ float tp[1024];
  __shared__ float t3[256];
  __shared__ float t4[9];
  int tid = threadIdx.x;
  for (int j = tid; j < 1024; j += 256) tp[j] = fdec(tpool[j]);
  __syncthreads();
  float acc = b3[tid];
  for (int d = 0; d < 1024; ++d) acc += tp[d]*w3[d*256+tid];
  t3[tid] = fmaxf(acc, 0.f);
  __syncthreads();
  if (tid < 9){
    float a = b4[tid];
    for (int d = 0; d < 256; ++d) a += t3[d]*w4[d*9+tid];
    t4[tid] = a;
  }
  __syncthreads();
  if (tid == 0){
    float a00=t4[0], a01=t4[1], a02=t4[2];
    float a10=t4[3], a11=t4[4], a12=t4[5];
    float a20=t4[6], a21=t4[7], a22=t4[8];
    // Householder QR, LAPACK sign convention (beta = -sign(alpha)*norm)
    float tau0 = 0.f, v1 = 0.f, v2 = 0.f;
    float xn2 = a10*a10 + a20*a20;
    if (xn2 > 0.f){
      float alpha = a00;
      float nrm = sqrtf(alpha*alpha + xn2);
      float beta = (alpha >= 0.f) ? -nrm : nrm;
      tau0 = (beta - alpha)/beta;
      float inv = 1.f/(alpha - beta);
      v1 = a10*inv; v2 = a20*inv;
      float s1 = a01 + v1*a11 + v2*a21; s1 *= tau0;
      a01 -= s1; a11 -= v1*s1; a21 -= v2*s1;
      float s2 = a02 + v1*a12 + v2*a22; s2 *= tau0;
      a02 -= s2; a12 -= v1*s2; a22 -= v2*s2;
      a00 = beta;
    }
    float tau1 = 0.f, wv = 0.f;
    float xn1 = a21*a21;
    if (xn1 > 0.f){
      float alpha = a11;
      float nrm = sqrtf(alpha*alpha + xn1);
      float beta = (alpha >= 0.f) ? -nrm : nrm;
      tau1 = (beta - alpha)/beta;
      wv = a21/(alpha - beta);
      float s = a12 + wv*a22; s *= tau1;
      a12 -= s; a22 -= wv*s;
      a11 = beta;
    }
    rout[0]=a00; rout[1]=a01; rout[2]=a02;
    rout[3]=0.f; rout[4]=a11; rout[5]=a12;
    rout[6]=0.f; rout[7]=0.f; rout[8]=a22;
    // Q = H0 * H1
    float M[3][3] = {{1,0,0},{0,1,0},{0,0,1}};
    M[1][1] -= tau1;     M[1][2] -= tau1*wv;
    M[2][1] -= tau1*wv;  M[2][2] -= tau1*wv*wv;
    #pragma unroll
    for (int c = 0; c < 3; ++c){
      float p = M[0][c] + v1*M[1][c] + v2*M[2][c];
      qmat[0*3+c] = M[0][c] - tau0*p;
      qmat[1*3+c] = M[1][c] - tau0*v1*p;
      qmat[2*3+c] = M[2][c] - tau0*v2*p;
    }
  }
}

__global__ __launch_bounds__(256) void xform_kernel(const float* __restrict__ pc,
    const float* __restrict__ q, float* __restrict__ x){
  int i = blockIdx.x*256 + threadIdx.x;
  if (i >= NP) return;
  float p0 = pc[i*3+0], p1 = pc[i*3+1], p2 = pc[i*3+2];
  x[i*3+0] = p0*q[0] + p1*q[3] + p2*q[6];
  x[i*3+1] = p0*q[1] + p1*q[4] + p2*q[7];
  x[i*3+2] = p0*q[2] + p1*q[5] + p2*q[8];
}

// pack transformed coords into coalescing-friendly layouts (L2-resident)
__global__ __launch_bounds__(256) void pack_kernel(const float* __restrict__ x,
    float4* __restrict__ p3, float2* __restrict__ pxy,
    float2* __restrict__ pyz, float2* __restrict__ pxz){
  int i = blockIdx.x*256 + threadIdx.x;
  if (i >= NP) return;
  float a = x[i*3], b = x[i*3+1], c = x[i*3+2];
  p3[i]  = make_float4(a, b, c, 0.f);
  pxy[i] = make_float2(a, b);
  pyz[i] = make_float2(b, c);
  pxz[i] = make_float2(a, c);
}

// ---------------- f32 GEMM: 128x128 tile, 8x8/thread, K-step 16 ----------------
// Thread (tx,ty) owns rows {ty*4..+3, 64+ty*4..+3} x cols {tx*4..+3, 64+tx*4..+3}.
// All K values are multiples of 16 (64/16/192/384) -> no K masking.
// STORE: write C; COLMAX: atomic col-max (encoded); BT: B is [ncols,K] row-major;
// D2EPI: out = bias[col] - 2*acc.
template<int STORE, int COLMAX, int BT, int D2EPI>
__global__ __launch_bounds__(256) void gemm_kernel(
    const float* __restrict__ A, int lda,
    const float* __restrict__ B, int ldb,
    const float* __restrict__ bias,
    float* __restrict__ C, unsigned* __restrict__ cmax,
    int kloop, int ncols, int remap_thresh, int remap_shift){
  __shared__ float As[16][132];
  __shared__ float Bs[16][132];
  int tid = threadIdx.x;
  int nbx = ncols >> 7;
  int bx = blockIdx.x % nbx, by = blockIdx.x / nbx;
  int tx = tid & 15, ty = tid >> 4;
  int row0 = by*128, col0 = bx*128;
  float acc[8][8];
  #pragma unroll
  for (int r = 0; r < 8; ++r)
    #pragma unroll
    for (int c = 0; c < 8; ++c) acc[r][c] = 0.f;

  for (int kt = 0; kt < kloop; kt += 16){
    // stage A: 128 rows x 16 k, transposed into As[k][m]; 512 float4 slots
    #pragma unroll
    for (int h = 0; h < 2; ++h){
      int s = tid*2 + h;
      int row = s >> 2, kq = s & 3;
      float4 av = *(const float4*)&A[(size_t)(row0+row)*lda + kt + kq*4];
      As[kq*4+0][row] = av.x; As[kq*4+1][row] = av.y;
      As[kq*4+2][row] = av.z; As[kq*4+3][row] = av.w;
    }
    if (BT){
      #pragma unroll
      for (int h = 0; h < 2; ++h){
        int s = tid*2 + h;
        int col = s >> 2, kq = s & 3;
        float4 bv = *(const float4*)&B[(size_t)(col0+col)*ldb + kt + kq*4];
        Bs[kq*4+0][col] = bv.x; Bs[kq*4+1][col] = bv.y;
        Bs[kq*4+2][col] = bv.z; Bs[kq*4+3][col] = bv.w;
      }
    } else {
      #pragma unroll
      for (int h = 0; h < 2; ++h){
        int s = tid*2 + h;
        int k = s >> 5, c4 = s & 31;
        int krow = kt + k;
        int brow = (krow >= remap_thresh) ? krow + remap_shift : krow;
        float4 bv = *(const float4*)&B[(size_t)brow*ldb + col0 + c4*4];
        *(float4*)&Bs[k][c4*4] = bv;
      }
    }
    __syncthreads();
    #pragma unroll
    for (int k = 0; k < 16; ++k){
      float4 a0 = *(const float4*)&As[k][ty*4];
      float4 a1 = *(const float4*)&As[k][64 + ty*4];
      float4 b0 = *(const float4*)&Bs[k][tx*4];
      float4 b1 = *(const float4*)&Bs[k][64 + tx*4];
      float av[8] = {a0.x,a0.y,a0.z,a0.w, a1.x,a1.y,a1.z,a1.w};
      float bv[8] = {b0.x,b0.y,b0.z,b0.w, b1.x,b1.y,b1.z,b1.w};
      #pragma unroll
      for (int r = 0; r < 8; ++r)
        #pragma unroll
        for (int c = 0; c < 8; ++c) acc[r][c] += av[r]*bv[c];
    }
    __syncthreads();
  }
  // epilogue
  float bvv[8];
  #pragma unroll
  for (int c = 0; c < 8; ++c){
    int cc = (c < 4) ? tx*4 + c : 64 + tx*4 + (c - 4);
    bvv[c] = bias[col0 + cc];
  }
  float val[8][8];
  #pragma unroll
  for (int r = 0; r < 8; ++r)
    #pragma unroll
    for (int c = 0; c < 8; ++c)
      val[r][c] = D2EPI ? (bvv[c] - 2.f*acc[r][c]) : (acc[r][c] + bvv[c]);
  if (STORE){
    #pragma unroll
    for (int r = 0; r < 8; ++r){
      int rr = (r < 4) ? ty*4 + r : 64 + ty*4 + (r - 4);
      float4 v0 = make_float4(val[r][0], val[r][1], val[r][2], val[r][3]);
      float4 v1 = make_float4(val[r][4], val[r][5], val[r][6], val[r][7]);
      *(float4*)&C[(size_t)(row0 + rr)*ncols + col0 + tx*4] = v0;
      *(float4*)&C[(size_t)(row0 + rr)*ncols + col0 + 64 + tx*4] = v1;
    }
  }
  if (COLMAX){
    float cm[8];
    #pragma unroll
    for (int c = 0; c < 8; ++c){
      float m = val[0][c];
      #pragma unroll
      for (int r = 1; r < 8; ++r) m = fmaxf(m, val[r][c]);
      cm[c] = m;
    }
    float* red = (float*)As;   // 16 x 128 flat
    #pragma unroll
    for (int c = 0; c < 8; ++c){
      int cc = (c < 4) ? tx*4 + c : 64 + tx*4 + (c - 4);
      red[ty*128 + cc] = cm[c];
    }
    __syncthreads();
    if (tid < 128){
      float m = red[tid];
      #pragma unroll
      for (int t = 1; t < 16; ++t) m = fmaxf(m, red[t*128 + tid]);
      atomicMax(&cmax[col0 + tid], fenc(m));
    }
  }
}

// ---------------- top-k extraction, register-resident ----------------
template<int K>
__device__ inline void extract_topk_reg(float (&v)[8][8], int lane,
    int* __restrict__ nbr_row){
  float gmin[8]; int gidx[8];
  #pragma unroll
  for (int g = 0; g < 8; ++g){
    float mv = v[g][0]; int mi = g*512 + lane;
    #pragma unroll
    for (int e = 1; e < 8; ++e){
      int j = (g*8 + e)*64 + lane;
      bool c = v[g][e] < mv;           // strict < keeps lowest j on ties
      mv = c ? v[g][e] : mv; mi = c ? j : mi;
    }
    gmin[g] = mv; gidx[g] = mi;
  }
  float lv = gmin[0]; int li = gidx[0];
  #pragma unroll
  for (int g = 1; g < 8; ++g){
    bool c = (gmin[g] < lv) || (gmin[g] == lv && gidx[g] < li);
    lv = c ? gmin[g] : lv; li = c ? gidx[g] : li;
  }
  int keep = 0;
  for (int r = 0; r < K; ++r){
    float vv = lv; int ii = li;
    #pragma unroll
    for (int off = 32; off; off >>= 1){
      float ov = __shfl_xor(vv, off);
      int oi = __shfl_xor(ii, off);
      bool c = (ov < vv) || (ov == vv && oi < ii);
      vv = c ? ov : vv; ii = c ? oi : ii;
    }
    if (lane == r) keep = ii;
    int gw = ii >> 9;                  // wave-uniform
    int ew = (ii >> 6) & 7;            // wave-uniform
    bool own = (ii & 63) == lane;
    #pragma unroll
    for (int g = 0; g < 8; ++g){
      if (g == gw){                    // uniform branch; one group taken
        #pragma unroll
        for (int e = 0; e < 8; ++e){
          bool kill = own && (ew == e);
          v[g][e] = kill ? 3e38f : v[g][e];
        }
        float mv = v[g][0]; int mi = g*512 + lane;
        #pragma unroll
        for (int e = 1; e < 8; ++e){
          int j = (g*8 + e)*64 + lane;
          bool c = v[g][e] < mv;
          mv = c ? v[g][e] : mv; mi = c ? j : mi;
        }
        gmin[g] = mv; gidx[g] = mi;
      }
    }
    lv = gmin[0]; li = gidx[0];
    #pragma unroll
    for (int g = 1; g < 8; ++g){
      bool c = (gmin[g] < lv) || (gmin[g] == lv && gidx[g] < li);
      lv = c ? gmin[g] : lv; li = c ? gidx[g] : li;
    }
  }
  if (lane < K) nbr_row[lane] = keep;
}

// all 4 coordinate kNN graphs in one launch; zero LDS, d2 straight to registers
__global__ __launch_bounds__(256) void knn_coord_kernel(const float4* __restrict__ p3,
    const float2* __restrict__ pxy, const float2* __restrict__ pyz,
    const float2* __restrict__ pxz, int* __restrict__ nbr4){
  int tid = threadIdx.x, lane = tid & 63, w = tid >> 6;
  int gsel = blockIdx.x >> 10;
  int i = (blockIdx.x & 1023)*4 + w;
  float v[8][8];
  if (gsel == 0){
    float4 q = p3[i];
    #pragma unroll
    for (int g = 0; g < 8; ++g)
      #pragma unroll
      for (int e = 0; e < 8; ++e){
        int j = (g*8 + e)*64 + lane;
        float4 p = p3[j];
        v[g][e] = (p.x*p.x + p.y*p.y + p.z*p.z) - 2.f*(p.x*q.x + p.y*q.y + p.z*q.z);
      }
  } else {
    const float2* pp = (gsel == 1) ? pxy : (gsel == 2) ? pyz : pxz;
    float2 q = pp[i];
    #pragma unroll
    for (int g = 0; g < 8; ++g)
      #pragma unroll
      for (int e = 0; e < 8; ++e){
        int j = (g*8 + e)*64 + lane;
        float2 p = pp[j];
        v[g][e] = (p.x*p.x + p.y*p.y) - 2.f*(p.x*q.x + p.y*q.y);
      }
  }
  extract_topk_reg<20>(v, lane, &nbr4[(size_t)gsel*NP*20 + i*20]);
}

// top-k from a precomputed (chunked) d2 matrix; zero LDS
template<int K>
__global__ __launch_bounds__(256) void topk_kernel(const float* __restrict__ d2m,
    int* __restrict__ nbr_chunk){
  int tid = threadIdx.x, lane = tid & 63, w = tid >> 6;
  int il = blockIdx.x*4 + w;
  float v[8][8];
  #pragma unroll
  for (int g = 0; g < 8; ++g)
    #pragma unroll
    for (int e = 0; e < 8; ++e)
      v[g][e] = d2m[(size_t)il*NP + (g*8 + e)*64 + lane];
  extract_topk_reg<K>(v, lane, &nbr_chunk[il*K]);
}

// ---------------- graph utilities ----------------
__global__ __launch_bounds__(256) void sq_kernel(const float* __restrict__ f, int ld, int D,
    float* __restrict__ sq){
  int i = blockIdx.x*256 + threadIdx.x;
  if (i >= NP) return;
  float s = 0.f;
  for (int c = 0; c < D; c += 4){
    float4 v = *(const float4*)&f[(size_t)i*ld + c];
    s += v.x*v.x + v.y*v.y + v.z*v.z + v.w*v.w;
  }
  sq[i] = s;
}

__global__ __launch_bounds__(256) void deg_kernel(const int* __restrict__ nbr, int total,
    int* __restrict__ deg){
  int e = blockIdx.x*256 + threadIdx.x;
  if (e < total) atomicAdd(&deg[nbr[e]], 1);
}

// degree counting for the 4 coordinate graphs in one launch
__global__ __launch_bounds__(256) void deg4_kernel(const int* __restrict__ nbr4,
    int* __restrict__ degs){
  int e = blockIdx.x*256 + threadIdx.x;
  int g = e / (NP*20);
  atomicAdd(&degs[g*NP + nbr4[e]], 1);
}

// DGL GraphConv norm='both', neighbor count templated; gathers batched 10-deep
template<int DIN, int DOUT, int KNB>
__global__ __launch_bounds__(256) void gc_kernel(const int* __restrict__ nbr, float kscale,
    const int* __restrict__ deg, const float* __restrict__ x, int ldx,
    const float* __restrict__ w, const float* __restrict__ b,
    float* __restrict__ out, int ldo){
  __shared__ float aggs[4][DIN];
  int tid = threadIdx.x, lane = tid & 63, wv = tid >> 6;
  int i = blockIdx.x*4 + wv;
  if (lane < DIN){
    float agg = 0.f;
    constexpr int CH = (KNB % 10 == 0) ? 10 : KNB;
    #pragma unroll
    for (int jj = 0; jj < KNB; jj += CH){
      int idx[CH]; float dv[CH]; float xv[CH];
      #pragma unroll
      for (int j = 0; j < CH; ++j) idx[j] = nbr[i*KNB + jj + j];
      #pragma unroll
      for (int j = 0; j < CH; ++j) dv[j] = (float)deg[idx[j]];
      #pragma unroll
      for (int j = 0; j < CH; ++j) xv[j] = x[(size_t)idx[j]*ldx + lane];
      #pragma unroll
      for (int j = 0; j < CH; ++j) agg += xv[j]*rsqrtf(fmaxf(dv[j], 1.f));
    }
    aggs[wv][lane] = agg * kscale;
  }
  __syncthreads();
  if (lane < DOUT){
    float o = b[lane];
    #pragma unroll 8
    for (int d = 0; d < DIN; ++d) o += aggs[wv][d] * w[d*DOUT + lane];
    out[(size_t)i*ldo + lane] = o;
  }
}

// ---------------- GAT pieces ----------------
__global__ __launch_bounds__(256) void crow_kernel(const unsigned* __restrict__ fc0max,
    const float* __restrict__ ws_, const float* __restrict__ wd_,
    float* __restrict__ c_s, float* __restrict__ c_d){
  __shared__ float hr[1024];
  int col = (blockIdx.x >> 1)*256 + threadIdx.x;
  const float* W = (blockIdx.x & 1) ? wd_ : ws_;
  float* outp = (blockIdx.x & 1) ? c_d : c_s;
  for (int j = threadIdx.x; j < 1024; j += 256) hr[j] = fdec(fc0max[j]);
  __syncthreads();
  float acc = 0.f;
  for (int d = 0; d < 1024; ++d) acc += hr[d]*W[(size_t)(192+d)*1024 + col];
  outp[col] = acc;
}

// GATv2: 512 blocks x 8 nodes; all 20 neighbor gathers in flight; single-pass softmax
__global__ __launch_bounds__(256) void gat_kernel(const int* __restrict__ nbr,
    const float* __restrict__ fs, const float* __restrict__ fd,
    const float* __restrict__ a, unsigned* __restrict__ gmax){
  int tid = threadIdx.x, lane = tid & 63, h = tid >> 6;
  float4 at = *(const float4*)&a[h*256 + lane*4];
  float runmax[4] = {-3e38f, -3e38f, -3e38f, -3e38f};
  for (int it = 0; it < 8; ++it){
    int i = blockIdx.x*8 + it;
    float4 fdv4 = *(const float4*)&fd[(size_t)i*1024 + h*256 + lane*4];
    int nb[20];
    #pragma unroll
    for (int j = 0; j < 20; ++j) nb[j] = nbr[i*20 + j];
    float4 fv[20];
    #pragma unroll
    for (int j = 0; j < 20; ++j)
      fv[j] = *(const float4*)&fs[(size_t)nb[j]*1024 + h*256 + lane*4];
    float p[20];
    #pragma unroll
    for (int j = 0; j < 20; ++j){
      float e0 = fv[j].x + fdv4.x; e0 = (e0 > 0.f) ? e0 : 0.2f*e0;
      float e1 = fv[j].y + fdv4.y; e1 = (e1 > 0.f) ? e1 : 0.2f*e1;
      float e2 = fv[j].z + fdv4.z; e2 = (e2 > 0.f) ? e2 : 0.2f*e2;
      float e3 = fv[j].w + fdv4.w; e3 = (e3 > 0.f) ? e3 : 0.2f*e3;
      p[j] = e0*at.x + e1*at.y + e2*at.z + e3*at.w;
    }
    #pragma unroll
    for (int off = 32; off; off >>= 1){
      #pragma unroll
      for (int j = 0; j < 20; ++j) p[j] += __shfl_xor(p[j], off);
    }
    float m = p[0];
    #pragma unroll
    for (int j = 1; j < 20; ++j) m = fmaxf(m, p[j]);
    float l = 0.f;
    float o[4] = {0.f, 0.f, 0.f, 0.f};
    #pragma unroll
    for (int j = 0; j < 20; ++j){
      float wj = __expf(p[j] - m);
      l += wj;
      o[0] += wj*fv[j].x; o[1] += wj*fv[j].y;
      o[2] += wj*fv[j].z; o[3] += wj*fv[j].w;
    }
    float inv = 1.f/l;
    #pragma unroll
    for (int c = 0; c < 4; ++c) runmax[c] = fmaxf(runmax[c], o[c]*inv);
  }
  #pragma unroll
  for (int c = 0; c < 4; ++c) atomicMax(&gmax[h*256 + lane*4 + c], fenc(runmax[c]));
}

__global__ __launch_bounds__(256) void head_kernel(const unsigned* __restrict__ gmax,
    const float* __restrict__ gb, const float* __restrict__ w1, const float* __restrict__ b1,
    const float* __restrict__ w2, const float* __restrict__ b2,
    const float* __restrict__ w3, const float* __restrict__ b3, float* __restrict__ out){
  __shared__ float hm[1024];
  __shared__ float s1[256];
  __shared__ float s2[64];
  int tid = threadIdx.x;
  for (int j = tid; j < 1024; j += 256) hm[j] = fdec(gmax[j]) + gb[j];
  __syncthreads();
  float acc = b1[tid];
  for (int d = 0; d < 1024; ++d) acc += hm[d]*w1[d*256+tid];
  s1[tid] = fmaxf(acc, 0.f);
  __syncthreads();
  if (tid < 64){
    float a2 = b2[tid];
    for (int d = 0; d < 256; ++d) a2 += s1[d]*w2[d*64+tid];
    s2[tid] = fmaxf(a2, 0.f);
  }
  __syncthreads();
  if (tid < 40){
    float a3 = b3[tid];
    for (int d = 0; d < 64; ++d) a3 += s2[d]*w3[d*40+tid];
    out[tid] = a3;
  }
}

// ---------------- launch ----------------
extern "C" void kernel_launch(void* const* d_in, const int* in_sizes, int n_in,
                              void* d_out, int out_size, void* d_ws, size_t ws_size,
                              hipStream_t stream){
  (void)in_sizes; (void)n_in; (void)out_size; (void)ws_size;
  const float* pc    = (const float*)d_in[0];
  const float* t_w1  = (const float*)d_in[1];
  const float* t_b1  = (const float*)d_in[2];
  const float* t_w2  = (const float*)d_in[3];
  const float* t_b2  = (const float*)d_in[4];
  const float* t_w3  = (const float*)d_in[5];
  const float* t_b3  = (const float*)d_in[6];
  const float* t_w4  = (const float*)d_in[7];
  const float* t_b4  = (const float*)d_in[8];
  const float* gc1_w = (const float*)d_in[9];
  const float* gc1_b = (const float*)d_in[10];
  const float* gc_w  = (const float*)d_in[11];
  const float* gc_b  = (const float*)d_in[12];
  const float* gp1_w = (const float*)d_in[13];
  const float* gp1_b = (const float*)d_in[14];
  const float* gp2_w = (const float*)d_in[15];
  const float* gp2_b = (const float*)d_in[16];
  const float* fc0_w = (const float*)d_in[17];
  const float* fc0_b = (const float*)d_in[18];
  const float* gat_ws= (const float*)d_in[19];
  const float* gat_wd= (const float*)d_in[20];
  const float* gat_a = (const float*)d_in[21];
  const float* gat_b = (const float*)d_in[22];
  const float* fc1_w = (const float*)d_in[23];
  const float* fc1_b = (const float*)d_in[24];
  const float* fc2_w = (const float*)d_in[25];
  const float* fc2_b = (const float*)d_in[26];
  const float* fc3_w = (const float*)d_in[27];
  const float* fc3_b = (const float*)d_in[28];
  float* out = (float*)d_out;

  char* basep = (char*)d_ws; size_t off = 0;
  auto alloc = [&](size_t bytes)->void*{
    void* p = basep + off; off += (bytes + 255) & ~(size_t)255; return p;
  };
  float* t1      = (float*)alloc((size_t)NP*64*4);
  float* x       = (float*)alloc((size_t)NP*3*4);
  float* qmat    = (float*)alloc(64);
  unsigned* tpool  = (unsigned*)alloc(1024*4);
  unsigned* fc0max = (unsigned*)alloc(1024*4);
  unsigned* gatmax = (unsigned*)alloc(1024*4);
  float* c_s     = (float*)alloc(1024*4);
  float* c_d     = (float*)alloc(1024*4);
  float4* p3     = (float4*)alloc((size_t)NP*16);
  float2* pxy    = (float2*)alloc((size_t)NP*8);
  float2* pyz    = (float2*)alloc((size_t)NP*8);
  float2* pxz    = (float2*)alloc((size_t)NP*8);
  float* tmp64   = (float*)alloc((size_t)NP*64*4);
  float* hfull   = (float*)alloc((size_t)NP*384*4);
  float* hp0     = (float*)alloc((size_t)NP*16*4);
  float* hp1     = (float*)alloc((size_t)NP*16*4);
  float* hp2     = (float*)alloc((size_t)NP*16*4);
  float* sqbuf   = (float*)alloc((size_t)NP*4);
  float* d2c     = (float*)alloc((size_t)2048*NP*4);   // 32 MB: 2048-row chunks
  int* nbr_coord = (int*)alloc((size_t)4*NP*20*4);     // [g0 | gxy | gyz | gxz]
  int* nbr_gf0   = (int*)alloc((size_t)NP*20*4);
  int* nbr_gf1   = (int*)alloc((size_t)NP*20*4);
  int* nbr_gp0   = (int*)alloc((size_t)NP*50*4);
  int* nbr_gp1   = (int*)alloc((size_t)NP*50*4);
  int* nbr_gp2   = (int*)alloc((size_t)NP*50*4);
  int* degs      = (int*)alloc((size_t)9*NP*4);
  float* fsb     = (float*)alloc((size_t)NP*1024*4);
  float* fdb     = (float*)alloc((size_t)NP*1024*4);

  int* nbr_g0  = nbr_coord + 0*NP*20;
  int* nbr_gxy = nbr_coord + 1*NP*20;
  int* nbr_gyz = nbr_coord + 2*NP*20;
  int* nbr_gxz = nbr_coord + 3*NP*20;

  const float KS20 = 0.22360679774997896f;   // 1/sqrt(20)
  const float KS50 = 0.14142135623730950f;   // 1/sqrt(50)
  const int NOMAP = 1 << 30;

  hipMemsetAsync(tpool,  0, 1024*4, stream);
  hipMemsetAsync(fc0max, 0, 1024*4, stream);
  hipMemsetAsync(gatmax, 0, 1024*4, stream);
  hipMemsetAsync(degs,   0, (size_t)9*NP*4, stream);

  // ---- T-net ----
  t1_kernel<<<NP/4, 256, 0, stream>>>(pc, t_w1, t_b1, t1);
  gemm_kernel<0,1,0,0><<<32*8, 256, 0, stream>>>(t1, 64, t_w2, 1024, t_b2,
      nullptr, tpool, 64, 1024, NOMAP, 0);
  tnet_tail_kernel<<<1, 256, 0, stream>>>(tpool, t_w3, t_b3, t_w4, t_b4, qmat, out + 40);
  xform_kernel<<<16, 256, 0, stream>>>(pc, qmat, x);
  pack_kernel<<<16, 256, 0, stream>>>(x, p3, pxy, pyz, pxz);

  // ---- coordinate kNN graphs (one launch, 4 graphs) ----
  knn_coord_kernel<<<4096, 256, 0, stream>>>(p3, pxy, pyz, pxz, nbr_coord);
  deg4_kernel<<<4*NP*20/256, 256, 0, stream>>>(nbr_coord, degs);

  // ---- main branch ----
  gc_kernel<3,64,20><<<NP/4, 256, 0, stream>>>(nbr_g0, KS20, degs + 0*NP, x, 3,
      gc1_w, gc1_b, tmp64, 64);
  gc_kernel<64,64,20><<<NP/4, 256, 0, stream>>>(nbr_g0, KS20, degs + 0*NP, tmp64, 64,
      gc_w + 0*4096, gc_b + 0*64, hfull + 0, 384);
  // gf0 = knn(h0, 20)  — 2048-row chunks
  sq_kernel<<<16, 256, 0, stream>>>(hfull + 0, 384, 64, sqbuf);
  for (int ch = 0; ch < 2; ++ch){
    gemm_kernel<1,0,1,1><<<16*32, 256, 0, stream>>>(hfull + (size_t)ch*2048*384, 384,
        hfull + 0, 384, sqbuf, d2c, nullptr, 64, NP, NOMAP, 0);
    topk_kernel<20><<<512, 256, 0, stream>>>(d2c, nbr_gf0 + ch*2048*20);
  }
  deg_kernel<<<(NP*20+255)/256, 256, 0, stream>>>(nbr_gf0, NP*20, degs + 4*NP);
  gc_kernel<64,64,20><<<NP/4, 256, 0, stream>>>(nbr_gf0, KS20, degs + 4*NP, hfull + 0, 384,
      gc_w + 1*4096, gc_b + 1*64, tmp64, 64);
  gc_kernel<64,64,20><<<NP/4, 256, 0, stream>>>(nbr_gf0, KS20, degs + 4*NP, tmp64, 64,
      gc_w + 2*4096, gc_b + 2*64, hfull + 64, 384);
  // gf1 = knn(h1, 20)
  sq_kernel<<<16, 256, 0, stream>>>(hfull + 64, 384, 64, sqbuf);
  for (int ch = 0; ch < 2; ++ch){
    gemm_kernel<1,0,1,1><<<16*32, 256, 0, stream>>>(hfull + 64 + (size_t)ch*2048*384, 384,
        hfull + 64, 384, sqbuf, d2c, nullptr, 64, NP, NOMAP, 0);
    topk_kernel<20><<<512, 256, 0, stream>>>(d2c, nbr_gf1 + ch*2048*20);
  }
  deg_kernel<<<(NP*20+255)/256, 256, 0, stream>>>(nbr_gf1, NP*20, degs + 5*NP);
  gc_kernel<64,64,20><<<NP/4, 256, 0, stream>>>(nbr_gf1, KS20, degs + 5*NP, hfull + 64, 384,
      gc_w + 3*4096, gc_b + 3*64, hfull + 128, 384);

  // ---- plane branches ----
  int* nbr_pl[3] = {nbr_gxy, nbr_gyz, nbr_gxz};
  int* nbr_gp[3] = {nbr_gp0, nbr_gp1, nbr_gp2};
  float* hps[3]  = {hp0, hp1, hp2};
  for (int i = 0; i < 3; ++i){
    gc_kernel<3,16,20><<<NP/4, 256, 0, stream>>>(nbr_pl[i], KS20, degs + (1+i)*NP, x, 3,
        gp1_w + i*48, gp1_b + i*16, hps[i], 16);
    sq_kernel<<<16, 256, 0, stream>>>(hps[i], 16, 16, sqbuf);
    for (int ch = 0; ch < 2; ++ch){
      gemm_kernel<1,0,1,1><<<16*32, 256, 0, stream>>>(hps[i] + (size_t)ch*2048*16, 16,
          hps[i], 16, sqbuf, d2c, nullptr, 16, NP, NOMAP, 0);
      topk_kernel<50><<<512, 256, 0, stream>>>(d2c, nbr_gp[i] + ch*2048*50);
    }
    deg_kernel<<<(NP*50+255)/256, 256, 0, stream>>>(nbr_gp[i], NP*50, degs + (6+i)*NP);
    gc_kernel<16,64,50><<<NP/4, 256, 0, stream>>>(nbr_gp[i], KS50, degs + (6+i)*NP,
        hps[i], 16, gp2_w + i*1024, gp2_b + i*64, hfull + 192 + 64*i, 384);
  }

  // ---- fc0 + max, then fs/fd GEMMs with h_ folded in as a per-column constant ----
  gemm_kernel<0,1,0,0><<<32*8, 256, 0, stream>>>(hfull, 384, fc0_w, 1024, fc0_b,
      nullptr, fc0max, 192, 1024, NOMAP, 0);
  crow_kernel<<<8, 256, 0, stream>>>(fc0max, gat_ws, gat_wd, c_s, c_d);
  gemm_kernel<1,0,0,0><<<32*8, 256, 0, stream>>>(hfull, 384, gat_ws, 1024, c_s,
      fsb, nullptr, 384, 1024, 192, 1024);
  gemm_kernel<1,0,0,0><<<32*8, 256, 0, stream>>>(hfull, 384, gat_wd, 1024, c_d,
      fdb, nullptr, 384, 1024, 192, 1024);

  // ---- GATv2 + head ----
  gat_kernel<<<NP/8, 256, 0, stream>>>(nbr_g0, fsb, fdb, gat_a, gatmax);
  head_kernel<<<1, 256, 0, stream>>>(gatmax, gat_b, fc1_w, fc1_b, fc2_w, fc2_b,
      fc3_w, fc3_b, out);
}